// Round 1
// baseline (5852.143 us; speedup 1.0000x reference)
//
#include <hip/hip_runtime.h>
#include <hip/hip_bf16.h>

// ---------------- problem constants ----------------
constexpr int Bb   = 2;
constexpr int Tt   = 1024;
constexpr int Dd   = 1024;
constexpr int Hh   = 16;
constexpr int KVH  = 4;
constexpr int HD   = 64;
constexpr int NTOK = Bb*Tt;              // 2048
constexpr int QKVD = (Hh+2*KVH)*HD;      // 1536
constexpr int Ee   = 8;
constexpr int Kk   = 2;
constexpr int HID  = 2816;
constexpr int CHh  = 4;
constexpr int CHD  = Dd/CHh;             // 256
constexpr int SL   = 3;
constexpr int NK   = NTOK*Kk;            // 4096
constexpr int CAP  = 1024;               // capacity
constexpr float EPS  = 1e-6f;
constexpr float AUXW = 0.01f;
constexpr float ZW   = 0.001f;

// ---------------- ws layout (float offsets) ----------------
constexpr size_t OFF_X1   = 0;            // 2,097,152
constexpr size_t OFF_XN   = 2097152;      // 2,097,152
constexpr size_t OFF_SEQ  = 4194304;      // 6,291,456
constexpr size_t OFF_TP   = 10485760;     // 4096
constexpr size_t OFF_PRIO = 10489856;     // 4096
constexpr size_t OFF_SCAL = 10493952;     // 32  (S_r[8], S_a[8], zsum)
constexpr size_t OFF_EIDS = 10494208;     // int 4096
constexpr size_t OFF_SLOT = 10498304;     // int 4096
constexpr size_t OFF_KEEP = 10502400;     // int 4096
constexpr size_t OFF_ROWL = 10506496;     // int 8192
constexpr size_t OFF_BIG  = 11534336;

// ---------------- helpers ----------------
__device__ __forceinline__ float blockReduceSum256(float v, float* red) {
  int tid = threadIdx.x;
  red[tid] = v; __syncthreads();
  for (int o = 128; o > 0; o >>= 1) {
    if (tid < o) red[tid] += red[tid + o];
    __syncthreads();
  }
  float r = red[0]; __syncthreads();
  return r;
}

// ---------------- init ----------------
__global__ void init_k(float* scal, int* rowl) {
  int i = blockIdx.x * 256 + threadIdx.x;
  if (i < 32) scal[i] = 0.f;
  if (i < Ee*CAP) rowl[i] = -1;
}

// ---------------- rmsnorm ----------------
__global__ __launch_bounds__(256) void rmsnorm_k(const float* __restrict__ in,
    const float* __restrict__ w, float* __restrict__ out) {
  __shared__ float red[256];
  int r = blockIdx.x;
  const float* x = in + (size_t)r * Dd;
  float s = 0.f;
  for (int d = threadIdx.x; d < Dd; d += 256) { float v = x[d]; s = fmaf(v, v, s); }
  float tot = blockReduceSum256(s, red);
  float scale = rsqrtf(tot / (float)Dd + EPS);
  for (int d = threadIdx.x; d < Dd; d += 256)
    out[(size_t)r * Dd + d] = x[d] * scale * w[d];
}

// ---------------- generic fp32 GEMM: C = [res +] act(A@B [+ bias]) ----------------
// A: MxKd row-major, B: KdxNc row-major. M multiple of 64, Nc multiple of 64, Kd of 16.
__global__ __launch_bounds__(256) void gemm_f32(
    const float* __restrict__ A, const float* __restrict__ Bw,
    const float* __restrict__ bias, const float* __restrict__ res,
    float* __restrict__ Cm, int Kd, int Nc, int act) {
  __shared__ float As[16][68];
  __shared__ float Bs[16][68];
  int row0 = blockIdx.y * 64, col0 = blockIdx.x * 64;
  int tid = threadIdx.x;
  int tx = tid & 15, ty = tid >> 4;
  float acc[4][4] = {};
  for (int k0 = 0; k0 < Kd; k0 += 16) {
    {
      int k = tid & 15, m0 = tid >> 4;
      #pragma unroll
      for (int p = 0; p < 4; p++) {
        int m = m0 + p * 16;
        As[k][m] = A[(size_t)(row0 + m) * Kd + k0 + k];
      }
    }
    {
      int c = tid & 63, kk0 = tid >> 6;
      #pragma unroll
      for (int p = 0; p < 4; p++) {
        int k = kk0 + p * 4;
        Bs[k][c] = Bw[(size_t)(k0 + k) * Nc + col0 + c];
      }
    }
    __syncthreads();
    #pragma unroll
    for (int k = 0; k < 16; k++) {
      float a[4], b[4];
      #pragma unroll
      for (int i = 0; i < 4; i++) a[i] = As[k][ty*4 + i];
      #pragma unroll
      for (int j = 0; j < 4; j++) b[j] = Bs[k][tx*4 + j];
      #pragma unroll
      for (int i = 0; i < 4; i++)
        #pragma unroll
        for (int j = 0; j < 4; j++)
          acc[i][j] = fmaf(a[i], b[j], acc[i][j]);
    }
    __syncthreads();
  }
  #pragma unroll
  for (int i = 0; i < 4; i++) {
    int r = row0 + ty*4 + i;
    #pragma unroll
    for (int j = 0; j < 4; j++) {
      int c = col0 + tx*4 + j;
      float v = acc[i][j];
      if (bias) v += bias[c];
      if (act == 1) v = 0.5f * v * (1.f + erff(v * 0.70710678118f));
      if (res)  v += res[(size_t)r * Nc + c];
      Cm[(size_t)r * Nc + c] = v;
    }
  }
}

// ---------------- RoPE (in-place on qkv buffer, q & k segments) ----------------
__global__ void rope_k(float* qkv, const float* __restrict__ cosb,
                       const float* __restrict__ sinb) {
  int idx = blockIdx.x * 256 + threadIdx.x;
  if (idx >= NTOK * 20 * 32) return;
  int i = idx & 31;
  int s = (idx >> 5) % 20;     // 0..15 q heads, 16..19 k heads (contiguous at s*64)
  int n = idx / (20 * 32);
  int t = n & (Tt - 1);
  float* p = qkv + (size_t)n * QKVD + s * HD + 2 * i;
  float a = p[0], b = p[1];
  float c = cosb[t * 32 + i], sn = sinb[t * 32 + i];
  p[0] = a * c - b * sn;
  p[1] = a * sn + b * c;
}

// ---------------- GQA causal attention (one block per (t,h,b)) ----------------
__global__ __launch_bounds__(256) void attn_k(const float* __restrict__ qkv,
                                              float* __restrict__ y) {
  int t = blockIdx.x, h = blockIdx.y, b = blockIdx.z;
  int n = b * Tt + t;
  int hkv = h >> 2;
  const float* qrow  = qkv + (size_t)n * QKVD + h * HD;
  const float* kbase = qkv + (size_t)b * Tt * QKVD + Hh * HD + hkv * HD;
  const float* vbase = kbase + KVH * HD;
  __shared__ float qs[64];
  __shared__ float sc[1024];
  __shared__ float red[256];
  int tid = threadIdx.x;
  if (tid < 64) qs[tid] = qrow[tid];
  __syncthreads();
  float lmax = -1e30f;
  for (int j = tid; j <= t; j += 256) {
    const float* kr = kbase + (size_t)j * QKVD;
    float d = 0.f;
    #pragma unroll
    for (int u = 0; u < 64; u++) d = fmaf(qs[u], kr[u], d);
    d *= 0.125f;
    sc[j] = d;
    lmax = fmaxf(lmax, d);
  }
  red[tid] = lmax; __syncthreads();
  for (int o = 128; o > 0; o >>= 1) {
    if (tid < o) red[tid] = fmaxf(red[tid], red[tid + o]);
    __syncthreads();
  }
  float m = red[0]; __syncthreads();
  float ls = 0.f;
  for (int j = tid; j <= t; j += 256) {
    float p = __expf(sc[j] - m);
    sc[j] = p;
    ls += p;
  }
  float S = blockReduceSum256(ls, red);
  float inv = 1.f / S;
  int d = tid & 63, part = tid >> 6;
  float acc = 0.f;
  for (int j = part; j <= t; j += 4)
    acc = fmaf(sc[j], vbase[(size_t)j * QKVD + d], acc);
  red[tid] = acc; __syncthreads();
  if (tid < 64) {
    float o = (red[tid] + red[tid+64] + red[tid+128] + red[tid+192]) * inv;
    y[(size_t)n * Dd + h * HD + d] = o;
  }
}

// ---------------- router: logits, top-2, probs, aux accumulators ----------------
__global__ __launch_bounds__(64) void route_k(const float* __restrict__ xn,
    const float* __restrict__ gw, float* tp, float* prio, int* eids, float* scal) {
  int n = blockIdx.x, lane = threadIdx.x;
  float acc[8] = {};
  for (int d = lane; d < Dd; d += 64) {
    float xd = xn[(size_t)n * Dd + d];
    #pragma unroll
    for (int e = 0; e < 8; e++) acc[e] = fmaf(xd, gw[d * 8 + e], acc[e]);
  }
  #pragma unroll
  for (int e = 0; e < 8; e++)
    for (int o = 32; o > 0; o >>= 1) acc[e] += __shfl_down(acc[e], o, 64);
  if (lane == 0) {
    float l[8];
    #pragma unroll
    for (int e = 0; e < 8; e++) l[e] = acc[e];
    int i0 = 0;
    for (int e = 1; e < 8; e++) if (l[e] > l[i0]) i0 = e;
    int i1 = -1;
    for (int e = 0; e < 8; e++) {
      if (e == i0) continue;
      if (i1 < 0 || l[e] > l[i1]) i1 = e;
    }
    float v0 = l[i0], v1 = l[i1];
    float ex1 = __expf(v1 - v0);
    float p0 = 1.f / (1.f + ex1);
    float p1 = ex1 / (1.f + ex1);
    float m = v0, se = 0.f;
    float rp[8];
    #pragma unroll
    for (int e = 0; e < 8; e++) { rp[e] = __expf(l[e] - m); se += rp[e]; }
    float invse = 1.f / se;
    #pragma unroll
    for (int e = 0; e < 8; e++) atomicAdd(&scal[e], rp[e] * invse);
    atomicAdd(&scal[8 + i0], p0);
    atomicAdd(&scal[8 + i1], p1);
    float zl = m + logf(se);
    atomicAdd(&scal[16], zl * zl);
    eids[n*2] = i0; eids[n*2+1] = i1;
    prio[n*2] = v0; prio[n*2+1] = v1;
    tp[n*2] = p0;   tp[n*2+1] = p1;
  }
}

// ---------------- stable rank within expert segment (lexsort equivalent) -------
__global__ void rank_k(const int* __restrict__ eids, const float* __restrict__ prio,
                       int* slot, int* keep, int* rowl) {
  int i = blockIdx.x * 256 + threadIdx.x;
  if (i >= NK) return;
  int e = eids[i];
  float p = prio[i];
  int r = 0;
  for (int j = 0; j < NK; j++) {
    if (eids[j] == e) {
      float pj = prio[j];
      if (pj > p || (pj == p && j < i)) r++;
    }
  }
  slot[i] = r;
  int kp = (r < CAP) ? 1 : 0;
  keep[i] = kp;
  if (kp) rowl[e * CAP + r] = i;
}

// ---------------- aux loss finalize ----------------
__global__ void aux_k(const float* __restrict__ scal, float* out_aux) {
  if (threadIdx.x == 0 && blockIdx.x == 0) {
    float bal = 0.f;
    for (int e = 0; e < 8; e++)
      bal += (scal[e] / (float)NTOK) * (scal[8 + e] / (float)NTOK);
    out_aux[0] = AUXW * bal * (float)Ee + ZW * (scal[16] / (float)NTOK);
  }
}

// ---------------- expert phase A: act = silu(g)*u, [g,u] = (2h)@w13[e] --------
__global__ __launch_bounds__(256) void expert_a_k(const float* __restrict__ xn,
    const float* __restrict__ w13, const int* __restrict__ rowl,
    float* __restrict__ actb) {
  int e = blockIdx.z;
  int row0 = blockIdx.y * 64, col0 = blockIdx.x * 64;
  const int* rl = rowl + e * CAP + row0;
  if (rl[0] < 0) return;
  const float* Bw = w13 + (size_t)e * Dd * (2 * HID);
  __shared__ float As[16][68];
  __shared__ float Bg[16][68];
  __shared__ float Bu[16][68];
  int tid = threadIdx.x, tx = tid & 15, ty = tid >> 4;
  float ag[4][4] = {}, au[4][4] = {};
  for (int k0 = 0; k0 < Dd; k0 += 16) {
    {
      int k = tid & 15, m0 = tid >> 4;
      #pragma unroll
      for (int p = 0; p < 4; p++) {
        int m = m0 + p * 16;
        int it = rl[m];
        As[k][m] = (it >= 0) ? 2.f * xn[(size_t)(it >> 1) * Dd + k0 + k] : 0.f;
      }
    }
    {
      int c = tid & 63, kk0 = tid >> 6;
      #pragma unroll
      for (int p = 0; p < 4; p++) {
        int k = kk0 + p * 4;
        const float* br = Bw + (size_t)(k0 + k) * (2 * HID) + col0 + c;
        Bg[k][c] = br[0];
        Bu[k][c] = br[HID];
      }
    }
    __syncthreads();
    #pragma unroll
    for (int k = 0; k < 16; k++) {
      float a[4], g[4], u[4];
      #pragma unroll
      for (int i = 0; i < 4; i++) a[i] = As[k][ty*4 + i];
      #pragma unroll
      for (int j = 0; j < 4; j++) { g[j] = Bg[k][tx*4 + j]; u[j] = Bu[k][tx*4 + j]; }
      #pragma unroll
      for (int i = 0; i < 4; i++)
        #pragma unroll
        for (int j = 0; j < 4; j++) {
          ag[i][j] = fmaf(a[i], g[j], ag[i][j]);
          au[i][j] = fmaf(a[i], u[j], au[i][j]);
        }
    }
    __syncthreads();
  }
  #pragma unroll
  for (int i = 0; i < 4; i++) {
    int it = rl[ty*4 + i];
    if (it < 0) continue;
    #pragma unroll
    for (int j = 0; j < 4; j++) {
      float g = ag[i][j], u = au[i][j];
      float sv = g / (1.f + __expf(-g)) * u;
      actb[(size_t)it * HID + col0 + tx*4 + j] = sv;
    }
  }
}

// ---------------- expert phase B: out = h + act@w2[e] ----------------
__global__ __launch_bounds__(256) void expert_b_k(const float* __restrict__ actb,
    const float* __restrict__ w2, const float* __restrict__ xn,
    const int* __restrict__ rowl, float* __restrict__ oflat) {
  int e = blockIdx.z;
  int row0 = blockIdx.y * 64, col0 = blockIdx.x * 64;
  const int* rl = rowl + e * CAP + row0;
  if (rl[0] < 0) return;
  const float* Bw = w2 + (size_t)e * HID * Dd;
  __shared__ float As[16][68];
  __shared__ float Bs[16][68];
  int tid = threadIdx.x, tx = tid & 15, ty = tid >> 4;
  float acc[4][4] = {};
  for (int k0 = 0; k0 < HID; k0 += 16) {
    {
      int k = tid & 15, m0 = tid >> 4;
      #pragma unroll
      for (int p = 0; p < 4; p++) {
        int m = m0 + p * 16;
        int it = rl[m];
        As[k][m] = (it >= 0) ? actb[(size_t)it * HID + k0 + k] : 0.f;
      }
    }
    {
      int c = tid & 63, kk0 = tid >> 6;
      #pragma unroll
      for (int p = 0; p < 4; p++) {
        int k = kk0 + p * 4;
        Bs[k][c] = Bw[(size_t)(k0 + k) * Dd + col0 + c];
      }
    }
    __syncthreads();
    #pragma unroll
    for (int k = 0; k < 16; k++) {
      float a[4], b[4];
      #pragma unroll
      for (int i = 0; i < 4; i++) a[i] = As[k][ty*4 + i];
      #pragma unroll
      for (int j = 0; j < 4; j++) b[j] = Bs[k][tx*4 + j];
      #pragma unroll
      for (int i = 0; i < 4; i++)
        #pragma unroll
        for (int j = 0; j < 4; j++)
          acc[i][j] = fmaf(a[i], b[j], acc[i][j]);
    }
    __syncthreads();
  }
  #pragma unroll
  for (int i = 0; i < 4; i++) {
    int it = rl[ty*4 + i];
    if (it < 0) continue;
    #pragma unroll
    for (int j = 0; j < 4; j++) {
      int c = col0 + tx*4 + j;
      oflat[(size_t)it * Dd + c] = xn[(size_t)(it >> 1) * Dd + c] + acc[i][j];
    }
  }
}

// ---------------- build collab sequences ----------------
__global__ void build_seq_k(const float* __restrict__ oflat, const int* __restrict__ keep,
                            const float* __restrict__ med, float* __restrict__ seq) {
  int idx = blockIdx.x * 256 + threadIdx.x;
  if (idx >= NTOK * SL * Dd) return;
  int d = idx & (Dd - 1);
  int s = (idx >> 10) % SL;
  int n = idx / (SL * Dd);
  float v;
  if (s == 0) v = med[d];
  else {
    int item = n * 2 + (s - 1);
    v = keep[item] ? oflat[(size_t)item * Dd + d] : 0.f;
  }
  seq[idx] = v;
}

// ---------------- collab attention (4 heads, sl=3, no mask) ----------------
__global__ __launch_bounds__(256) void collab_attn_k(const float* __restrict__ q,
    const float* __restrict__ k, const float* __restrict__ v, float* __restrict__ o) {
  int n = blockIdx.x, tid = threadIdx.x;
  int h = tid >> 6, lane = tid & 63;
  __shared__ float s[4][9];
  size_t base = (size_t)n * SL * Dd;
  #pragma unroll
  for (int i = 0; i < 3; i++)
    #pragma unroll
    for (int j = 0; j < 3; j++) {
      float d = 0.f;
      #pragma unroll
      for (int uu = 0; uu < 4; uu++) {
        int u = lane + uu * 64;
        d = fmaf(q[base + i*Dd + h*CHD + u], k[base + j*Dd + h*CHD + u], d);
      }
      for (int off = 32; off > 0; off >>= 1) d += __shfl_down(d, off, 64);
      if (lane == 0) s[h][i*3 + j] = d * 0.0625f;  // 1/sqrt(256)
    }
  __syncthreads();
  #pragma unroll
  for (int i = 0; i < 3; i++) {
    float s0 = s[h][i*3+0], s1 = s[h][i*3+1], s2 = s[h][i*3+2];
    float m = fmaxf(s0, fmaxf(s1, s2));
    float e0 = __expf(s0 - m), e1 = __expf(s1 - m), e2 = __expf(s2 - m);
    float inv = 1.f / (e0 + e1 + e2);
    e0 *= inv; e1 *= inv; e2 *= inv;
    #pragma unroll
    for (int dd = 0; dd < 4; dd++) {
      int u = lane + dd * 64;
      float ov = e0 * v[base + 0*Dd + h*CHD + u]
               + e1 * v[base + 1*Dd + h*CHD + u]
               + e2 * v[base + 2*Dd + h*CHD + u];
      o[base + i*Dd + h*CHD + u] = ov;
    }
  }
}

// ---------------- gated fusion ----------------
__global__ __launch_bounds__(256) void fusion_k(const float* __restrict__ seq,
    const float* __restrict__ tp, const float* __restrict__ fg_w,
    const float* __restrict__ fg_b, float* __restrict__ fused) {
  __shared__ float red[256];
  int n = blockIdx.x, tid = threadIdx.x;
  const float* med = seq + (size_t)n * SL * Dd;
  const float* ex0 = med + Dd;
  const float* ex1 = med + 2 * Dd;
  float part = 0.f;
  for (int d = tid; d < Dd; d += 256) part = fmaf(med[d], fg_w[d], part);
  float dot = blockReduceSum256(part, red);
  float g = 1.f / (1.f + __expf(-(dot + fg_b[0])));
  float p0 = tp[n*2], p1 = tp[n*2+1];
  for (int d = tid; d < Dd; d += 256) {
    float w = p0 * ex0[d] + p1 * ex1[d];
    fused[(size_t)n * Dd + d] = g * med[d] + (1.f - g) * w;
  }
}

// ---------------- host launch ----------------
extern "C" void kernel_launch(void* const* d_in, const int* in_sizes, int n_in,
                              void* d_out, int out_size, void* d_ws, size_t ws_size,
                              hipStream_t stream) {
  const float* x_in   = (const float*)d_in[0];
  const float* fcos   = (const float*)d_in[1];
  const float* fsin   = (const float*)d_in[2];
  const float* ln1_w  = (const float*)d_in[3];
  const float* ln2_w  = (const float*)d_in[4];
  const float* w_qkv  = (const float*)d_in[5];
  const float* w_o    = (const float*)d_in[6];
  const float* gate_w = (const float*)d_in[7];
  const float* e_w13  = (const float*)d_in[8];
  const float* e_w2   = (const float*)d_in[9];
  const float* medi   = (const float*)d_in[10];
  const float* mwq    = (const float*)d_in[11];
  const float* mwk    = (const float*)d_in[12];
  const float* mwv    = (const float*)d_in[13];
  const float* mbq    = (const float*)d_in[14];
  const float* mbk    = (const float*)d_in[15];
  const float* mbv    = (const float*)d_in[16];
  const float* mwo    = (const float*)d_in[17];
  const float* mbo    = (const float*)d_in[18];
  const float* cn1_w  = (const float*)d_in[19];
  const float* cn2_w  = (const float*)d_in[20];
  const float* cf1_w  = (const float*)d_in[21];
  const float* cf2_w  = (const float*)d_in[22];
  const float* fg_w   = (const float*)d_in[23];
  const float* fg_b   = (const float*)d_in[24];
  const float* moe_ow = (const float*)d_in[25];

  float* ws = (float*)d_ws;
  float* x1   = ws + OFF_X1;
  float* xn   = ws + OFF_XN;
  float* seq  = ws + OFF_SEQ;
  float* tp   = ws + OFF_TP;
  float* prio = ws + OFF_PRIO;
  float* scal = ws + OFF_SCAL;
  int*   eids = (int*)(ws + OFF_EIDS);
  int*   slot = (int*)(ws + OFF_SLOT);
  int*   keep = (int*)(ws + OFF_KEEP);
  int*   rowl = (int*)(ws + OFF_ROWL);
  float* big  = ws + OFF_BIG;

  float* hn   = big;
  float* qkvb = big + 2097152;
  float* yb   = big + 5242880;
  float* actb = big;                    // reuses hn/qkv/y after attention
  float* oflat= big + 11534336;
  float* nrm  = big;                    // collab temporaries
  float* cq   = big + 6291456;
  float* ck   = big + 12582912;
  float* cv   = big + 18874368;
  float* atno = big;                    // overwrites nrm (dead)
  float* nrm2 = big + 6291456;          // overwrites cq (dead)
  float* ffh  = big;                    // overwrites atno (dead)
  float* fused= big;

  float* out_x   = (float*)d_out;
  float* out_aux = out_x + (size_t)NTOK * Dd;

  dim3 blk(256);

  hipLaunchKernelGGL(init_k, dim3(32), blk, 0, stream, scal, rowl);

  // attention block
  hipLaunchKernelGGL(rmsnorm_k, dim3(NTOK), blk, 0, stream, x_in, ln1_w, hn);
  hipLaunchKernelGGL(gemm_f32, dim3(QKVD/64, NTOK/64), blk, 0, stream,
                     hn, w_qkv, (const float*)nullptr, (const float*)nullptr,
                     qkvb, Dd, QKVD, 0);
  hipLaunchKernelGGL(rope_k, dim3((NTOK*20*32)/256), blk, 0, stream, qkvb, fcos, fsin);
  hipLaunchKernelGGL(attn_k, dim3(Tt, Hh, Bb), blk, 0, stream, qkvb, yb);
  hipLaunchKernelGGL(gemm_f32, dim3(Dd/64, NTOK/64), blk, 0, stream,
                     yb, w_o, (const float*)nullptr, x_in, x1, Dd, Dd, 0);

  // routing
  hipLaunchKernelGGL(rmsnorm_k, dim3(NTOK), blk, 0, stream, x1, ln2_w, xn);
  hipLaunchKernelGGL(route_k, dim3(NTOK), dim3(64), 0, stream,
                     xn, gate_w, tp, prio, eids, scal);
  hipLaunchKernelGGL(rank_k, dim3(NK/256), blk, 0, stream, eids, prio, slot, keep, rowl);
  hipLaunchKernelGGL(aux_k, dim3(1), dim3(64), 0, stream, scal, out_aux);

  // expert FFN
  hipLaunchKernelGGL(expert_a_k, dim3(HID/64, CAP/64, Ee), blk, 0, stream,
                     xn, e_w13, rowl, actb);
  hipLaunchKernelGGL(expert_b_k, dim3(Dd/64, CAP/64, Ee), blk, 0, stream,
                     actb, e_w2, xn, rowl, oflat);

  // collab transformer
  hipLaunchKernelGGL(build_seq_k, dim3((NTOK*SL*Dd)/256), blk, 0, stream,
                     oflat, keep, medi, seq);
  for (int r = 0; r < 2; r++) {
    hipLaunchKernelGGL(rmsnorm_k, dim3(NTOK*SL), blk, 0, stream, seq, cn1_w, nrm);
    hipLaunchKernelGGL(gemm_f32, dim3(Dd/64, (NTOK*SL)/64), blk, 0, stream,
                       nrm, mwq, mbq, (const float*)nullptr, cq, Dd, Dd, 0);
    hipLaunchKernelGGL(gemm_f32, dim3(Dd/64, (NTOK*SL)/64), blk, 0, stream,
                       nrm, mwk, mbk, (const float*)nullptr, ck, Dd, Dd, 0);
    hipLaunchKernelGGL(gemm_f32, dim3(Dd/64, (NTOK*SL)/64), blk, 0, stream,
                       nrm, mwv, mbv, (const float*)nullptr, cv, Dd, Dd, 0);
    hipLaunchKernelGGL(collab_attn_k, dim3(NTOK), blk, 0, stream, cq, ck, cv, atno);
    hipLaunchKernelGGL(gemm_f32, dim3(Dd/64, (NTOK*SL)/64), blk, 0, stream,
                       atno, mwo, mbo, seq, seq, Dd, Dd, 0);
    hipLaunchKernelGGL(rmsnorm_k, dim3(NTOK*SL), blk, 0, stream, seq, cn2_w, nrm2);
    hipLaunchKernelGGL(gemm_f32, dim3(Dd/64, (NTOK*SL)/64), blk, 0, stream,
                       nrm2, cf1_w, (const float*)nullptr, (const float*)nullptr,
                       ffh, Dd, Dd, 1);
    hipLaunchKernelGGL(gemm_f32, dim3(Dd/64, (NTOK*SL)/64), blk, 0, stream,
                       ffh, cf2_w, (const float*)nullptr, seq, seq, Dd, Dd, 0);
  }

  // fusion + final projection
  hipLaunchKernelGGL(fusion_k, dim3(NTOK), blk, 0, stream, seq, tp, fg_w, fg_b, fused);
  hipLaunchKernelGGL(gemm_f32, dim3(Dd/64, NTOK/64), blk, 0, stream,
                     fused, moe_ow, (const float*)nullptr, x1, out_x, Dd, Dd, 0);
}

// Round 2
// 3170.115 us; speedup vs baseline: 1.8460x; 1.8460x over previous
//
#include <hip/hip_runtime.h>

// ---------------- problem constants ----------------
constexpr int Bb   = 2;
constexpr int Tt   = 1024;
constexpr int Dd   = 1024;
constexpr int Hh   = 16;
constexpr int KVH  = 4;
constexpr int HD   = 64;
constexpr int NTOK = Bb*Tt;              // 2048
constexpr int QKVD = (Hh+2*KVH)*HD;      // 1536
constexpr int Ee   = 8;
constexpr int HID  = 2816;
constexpr int NK   = NTOK*2;             // 4096
constexpr int CAP  = 1024;
constexpr float EPS  = 1e-6f;
constexpr float AUXW = 0.01f;
constexpr float ZW   = 0.001f;

typedef short bf16s;
typedef __attribute__((ext_vector_type(8))) short s8;
typedef __attribute__((ext_vector_type(4))) short s4;
typedef __attribute__((ext_vector_type(4))) float f4;

__device__ __forceinline__ short f2bf(float f) {
  union { float f; unsigned u; } v; v.f = f;
  unsigned r = (v.u + 0x7fffu + ((v.u >> 16) & 1u)) >> 16;
  return (short)r;
}
__device__ __forceinline__ float bf2f(short s) {
  union { unsigned u; float f; } v; v.u = ((unsigned)(unsigned short)s) << 16;
  return v.f;
}
__device__ __forceinline__ void gload16(const void* g, void* l) {
  __builtin_amdgcn_global_load_lds(
      (const __attribute__((address_space(1))) void*)g,
      (__attribute__((address_space(3))) void*)l, 16, 0, 0);
}

// ---------------- ws layout (byte offsets) ----------------
constexpr size_t B_W13T = 0;
constexpr size_t S_W13T = (size_t)Ee*2*HID*Dd*2;          // 92,274,688
constexpr size_t B_W2T  = B_W13T + S_W13T;
constexpr size_t S_W2T  = (size_t)Ee*Dd*HID*2;            // 46,137,344
constexpr size_t B_WQKVT= B_W2T + S_W2T;
constexpr size_t S_WQKVT= (size_t)QKVD*Dd*2;
constexpr size_t B_WOT  = B_WQKVT + S_WQKVT;
constexpr size_t S_SQ   = (size_t)Dd*Dd*2;
constexpr size_t B_MWQT = B_WOT + S_SQ;
constexpr size_t B_MWKT = B_MWQT + S_SQ;
constexpr size_t B_MWVT = B_MWKT + S_SQ;
constexpr size_t B_MWOT = B_MWVT + S_SQ;
constexpr size_t B_CF1T = B_MWOT + S_SQ;
constexpr size_t B_CF2T = B_CF1T + S_SQ;
constexpr size_t B_MOET = B_CF2T + S_SQ;
constexpr size_t B_X1   = B_MOET + S_SQ;
constexpr size_t B_XN   = B_X1 + (size_t)NTOK*Dd*4;
constexpr size_t B_XNB  = B_XN + (size_t)NTOK*Dd*4;
constexpr size_t B_SEQ  = B_XNB + (size_t)NTOK*Dd*2;
constexpr size_t B_TP   = B_SEQ + (size_t)NTOK*3*Dd*4;
constexpr size_t B_PRIO = B_TP + (size_t)NK*4;
constexpr size_t B_SCAL = B_PRIO + (size_t)NK*4;
constexpr size_t B_EIDS = B_SCAL + 256;
constexpr size_t B_ROWL = B_EIDS + (size_t)NK*4;
constexpr size_t B_BIG  = B_ROWL + (size_t)Ee*CAP*4;
// BIG overlays
constexpr size_t BG_HNB  = 0;
constexpr size_t BG_QKVB = (size_t)NTOK*Dd*2;             // 4,194,304
constexpr size_t BG_YB   = BG_QKVB + (size_t)NTOK*QKVD*4; // 16,777,216
constexpr size_t BG_XG   = 0;
constexpr size_t BG_ACTB = (size_t)Ee*CAP*Dd*2;           // 16,777,216
constexpr size_t BG_NRM  = 0;
constexpr size_t BG_CQ   = (size_t)NTOK*3*Dd*2;           // 12,582,912
constexpr size_t BG_CK   = BG_CQ*2;
constexpr size_t BG_CV   = BG_CQ*3;
constexpr size_t BG_ATNO = BG_CQ*4;
constexpr size_t BG_FFH  = BG_CQ;     // reuse cq (dead after collab_attn)
constexpr size_t BG_FUSE = BG_CQ*2;   // reuse ck

// ---------------- helpers ----------------
__device__ __forceinline__ float blockReduceSum256(float v, float* red) {
  int tid = threadIdx.x;
  red[tid] = v; __syncthreads();
  for (int o = 128; o > 0; o >>= 1) {
    if (tid < o) red[tid] += red[tid + o];
    __syncthreads();
  }
  float r = red[0]; __syncthreads();
  return r;
}

// ---------------- init ----------------
__global__ void init_k(float* scal, int* rowl) {
  int i = blockIdx.x * 256 + threadIdx.x;
  if (i < 32) scal[i] = 0.f;
  if (i < Ee*CAP) rowl[i] = -1;
}

// ---------------- transpose+cast: src f32 [K][N] -> dst bf16 [N][K] ----------
__global__ __launch_bounds__(256) void transpose_cast_k(
    const float* __restrict__ src, bf16s* __restrict__ dst,
    int K, int N, size_t sstride, size_t dstride) {
  __shared__ float t[32][33];
  src += blockIdx.z * sstride; dst += blockIdx.z * dstride;
  int n0 = blockIdx.x * 32, k0 = blockIdx.y * 32;
  int tx = threadIdx.x & 31, ty = threadIdx.x >> 5;
  #pragma unroll
  for (int p = 0; p < 4; p++)
    t[ty + p*8][tx] = src[(size_t)(k0 + ty + p*8) * N + n0 + tx];
  __syncthreads();
  #pragma unroll
  for (int p = 0; p < 4; p++)
    dst[(size_t)(n0 + ty + p*8) * K + k0 + tx] = f2bf(t[tx][ty + p*8]);
}

// ---------------- rmsnorm (f32 in; optional f32 out + bf16 out) --------------
__global__ __launch_bounds__(256) void rmsnorm_k(const float* __restrict__ in,
    const float* __restrict__ w, float* __restrict__ outf, bf16s* __restrict__ outb) {
  __shared__ float red[256];
  int r = blockIdx.x, tid = threadIdx.x;
  float4 v = ((const float4*)(in + (size_t)r * Dd))[tid];
  float s = v.x*v.x + v.y*v.y + v.z*v.z + v.w*v.w;
  float tot = blockReduceSum256(s, red);
  float scale = rsqrtf(tot / (float)Dd + EPS);
  float4 wv = ((const float4*)w)[tid];
  float o0 = v.x*scale*wv.x, o1 = v.y*scale*wv.y, o2 = v.z*scale*wv.z, o3 = v.w*scale*wv.w;
  if (outf) ((float4*)(outf + (size_t)r * Dd))[tid] = make_float4(o0, o1, o2, o3);
  if (outb) {
    s4 p; p[0] = f2bf(o0); p[1] = f2bf(o1); p[2] = f2bf(o2); p[3] = f2bf(o3);
    ((s4*)(outb + (size_t)r * Dd))[tid] = p;
  }
}

// ---------------- MFMA GEMM: C = [res +] act(A @ Bt^T [+ bias]) --------------
// A: [M][K] bf16, Bt: [N][K] bf16. 128x128 tile, BK=32, 4 waves.
template<bool OUTBF, bool GELU>
__global__ __launch_bounds__(256) void gemm_bt(
    const bf16s* __restrict__ A, const bf16s* __restrict__ Bt,
    const float* __restrict__ bias, const float* __restrict__ res,
    void* __restrict__ Cout, int M, int N, int K) {
  __shared__ bf16s As[128*32];
  __shared__ bf16s Bs[128*32];
  const int tid = threadIdx.x, w = tid >> 6, lane = tid & 63;
  const int row0 = blockIdx.y * 128, col0 = blockIdx.x * 128;
  const int wm = w >> 1, wn = w & 1;
  f4 acc[4][4] = {};
  const int sr = lane >> 2, sc = (lane & 3) * 8;
  for (int k0 = 0; k0 < K; k0 += 32) {
    #pragma unroll
    for (int i = 0; i < 2; i++) {
      int seg = w*2 + i;
      gload16(A  + (size_t)(row0 + seg*16 + sr) * K + k0 + sc, &As[seg*512]);
      gload16(Bt + (size_t)(col0 + seg*16 + sr) * K + k0 + sc, &Bs[seg*512]);
    }
    __syncthreads();
    const int fr = lane & 15, kb = lane >> 4;
    s8 a[4], b[4];
    #pragma unroll
    for (int mi = 0; mi < 4; mi++) a[mi] = *(const s8*)&As[(wm*64 + mi*16 + fr)*32 + kb*8];
    #pragma unroll
    for (int ni = 0; ni < 4; ni++) b[ni] = *(const s8*)&Bs[(wn*64 + ni*16 + fr)*32 + kb*8];
    #pragma unroll
    for (int mi = 0; mi < 4; mi++)
      #pragma unroll
      for (int ni = 0; ni < 4; ni++)
        acc[mi][ni] = __builtin_amdgcn_mfma_f32_16x16x32_bf16(a[mi], b[ni], acc[mi][ni], 0, 0, 0);
    __syncthreads();
  }
  const int cr = (lane >> 4) * 4, cc = lane & 15;
  #pragma unroll
  for (int mi = 0; mi < 4; mi++) {
    #pragma unroll
    for (int ni = 0; ni < 4; ni++) {
      int col = col0 + wn*64 + ni*16 + cc;
      float bv = bias ? bias[col] : 0.f;
      #pragma unroll
      for (int q = 0; q < 4; q++) {
        int row = row0 + wm*64 + mi*16 + cr + q;
        float v = acc[mi][ni][q] + bv;
        if (GELU) v = 0.5f * v * (1.f + erff(v * 0.70710678118f));
        if (res) v += res[(size_t)row * N + col];
        if (OUTBF) ((bf16s*)Cout)[(size_t)row * N + col] = f2bf(v);
        else       ((float*)Cout)[(size_t)row * N + col] = v;
      }
    }
  }
}

// ---------------- expert w13 fused (g,u) GEMM: actb = silu(2g)*(2u) ----------
// tile 128 rows x 64 cols; waves 2x2 (row-half x col-half-32)
__global__ __launch_bounds__(256) void gemm_w13(
    const bf16s* __restrict__ xg, const bf16s* __restrict__ w13t,
    const int* __restrict__ rowl, bf16s* __restrict__ actb) {
  const int e = blockIdx.z;
  const int row0 = blockIdx.y * 128, col0 = blockIdx.x * 64;
  if (rowl[e*CAP + row0] < 0) return;
  __shared__ bf16s As[128*32];
  __shared__ bf16s Bgs[64*32];
  __shared__ bf16s Bus[64*32];
  const int tid = threadIdx.x, w = tid >> 6, lane = tid & 63;
  const int wm = w >> 1, wn = w & 1;
  const bf16s* Ab = xg + (size_t)e * CAP * Dd;
  const bf16s* Wg = w13t + (size_t)e * (2*HID) * Dd + (size_t)col0 * Dd;
  const bf16s* Wu = Wg + (size_t)HID * Dd;
  f4 ag[4][2] = {}, au[4][2] = {};
  const int sr = lane >> 2, sc = (lane & 3) * 8;
  for (int k0 = 0; k0 < Dd; k0 += 32) {
    #pragma unroll
    for (int i = 0; i < 2; i++) {
      int seg = w*2 + i;
      gload16(Ab + (size_t)(row0 + seg*16 + sr) * Dd + k0 + sc, &As[seg*512]);
    }
    gload16(Wg + (size_t)(w*16 + sr) * Dd + k0 + sc, &Bgs[w*512]);
    gload16(Wu + (size_t)(w*16 + sr) * Dd + k0 + sc, &Bus[w*512]);
    __syncthreads();
    const int fr = lane & 15, kb = lane >> 4;
    s8 a[4], bg[2], bu[2];
    #pragma unroll
    for (int mi = 0; mi < 4; mi++) a[mi] = *(const s8*)&As[(wm*64 + mi*16 + fr)*32 + kb*8];
    #pragma unroll
    for (int ni = 0; ni < 2; ni++) {
      bg[ni] = *(const s8*)&Bgs[(wn*32 + ni*16 + fr)*32 + kb*8];
      bu[ni] = *(const s8*)&Bus[(wn*32 + ni*16 + fr)*32 + kb*8];
    }
    #pragma unroll
    for (int mi = 0; mi < 4; mi++)
      #pragma unroll
      for (int ni = 0; ni < 2; ni++) {
        ag[mi][ni] = __builtin_amdgcn_mfma_f32_16x16x32_bf16(a[mi], bg[ni], ag[mi][ni], 0, 0, 0);
        au[mi][ni] = __builtin_amdgcn_mfma_f32_16x16x32_bf16(a[mi], bu[ni], au[mi][ni], 0, 0, 0);
      }
    __syncthreads();
  }
  const int cr = (lane >> 4) * 4, cc = lane & 15;
  #pragma unroll
  for (int mi = 0; mi < 4; mi++)
    #pragma unroll
    for (int ni = 0; ni < 2; ni++)
      #pragma unroll
      for (int q = 0; q < 4; q++) {
        int row = row0 + wm*64 + mi*16 + cr + q;
        int col = col0 + wn*32 + ni*16 + cc;
        float g = 2.f * ag[mi][ni][q], u = 2.f * au[mi][ni][q];
        float sv = g / (1.f + __expf(-g)) * u;
        actb[((size_t)e*CAP + row) * HID + col] = f2bf(sv);
      }
}

// ---------------- expert w2 GEMM with scatter into seq -----------------------
__global__ __launch_bounds__(256) void gemm_w2(
    const bf16s* __restrict__ actb, const bf16s* __restrict__ w2t,
    const float* __restrict__ xn, const int* __restrict__ rowl,
    float* __restrict__ seq) {
  const int e = blockIdx.z;
  const int row0 = blockIdx.y * 128, col0 = blockIdx.x * 128;
  if (rowl[e*CAP + row0] < 0) return;
  __shared__ bf16s As[128*32];
  __shared__ bf16s Bs[128*32];
  const int tid = threadIdx.x, w = tid >> 6, lane = tid & 63;
  const int wm = w >> 1, wn = w & 1;
  const bf16s* Ab = actb + (size_t)e * CAP * HID;
  const bf16s* Bt = w2t + (size_t)e * Dd * HID;
  f4 acc[4][4] = {};
  const int sr = lane >> 2, sc = (lane & 3) * 8;
  for (int k0 = 0; k0 < HID; k0 += 32) {
    #pragma unroll
    for (int i = 0; i < 2; i++) {
      int seg = w*2 + i;
      gload16(Ab + (size_t)(row0 + seg*16 + sr) * HID + k0 + sc, &As[seg*512]);
      gload16(Bt + (size_t)(col0 + seg*16 + sr) * HID + k0 + sc, &Bs[seg*512]);
    }
    __syncthreads();
    const int fr = lane & 15, kb = lane >> 4;
    s8 a[4], b[4];
    #pragma unroll
    for (int mi = 0; mi < 4; mi++) a[mi] = *(const s8*)&As[(wm*64 + mi*16 + fr)*32 + kb*8];
    #pragma unroll
    for (int ni = 0; ni < 4; ni++) b[ni] = *(const s8*)&Bs[(wn*64 + ni*16 + fr)*32 + kb*8];
    #pragma unroll
    for (int mi = 0; mi < 4; mi++)
      #pragma unroll
      for (int ni = 0; ni < 4; ni++)
        acc[mi][ni] = __builtin_amdgcn_mfma_f32_16x16x32_bf16(a[mi], b[ni], acc[mi][ni], 0, 0, 0);
    __syncthreads();
  }
  const int cr = (lane >> 4) * 4, cc = lane & 15;
  #pragma unroll
  for (int mi = 0; mi < 4; mi++)
    #pragma unroll
    for (int q = 0; q < 4; q++) {
      int row = row0 + wm*64 + mi*16 + cr + q;
      int it = rowl[e*CAP + row];
      if (it < 0) continue;
      int n = it >> 1, s = 1 + (it & 1);
      #pragma unroll
      for (int ni = 0; ni < 4; ni++) {
        int col = col0 + wn*64 + ni*16 + cc;
        seq[((size_t)n*3 + s) * Dd + col] = xn[(size_t)n * Dd + col] + acc[mi][ni][q];
      }
    }
}

// ---------------- RoPE ----------------
__global__ void rope_k(float* qkv, const float* __restrict__ cosb,
                       const float* __restrict__ sinb) {
  int idx = blockIdx.x * 256 + threadIdx.x;
  if (idx >= NTOK * 20 * 32) return;
  int i = idx & 31;
  int s = (idx >> 5) % 20;
  int n = idx / (20 * 32);
  int t = n & (Tt - 1);
  float* p = qkv + (size_t)n * QKVD + s * HD + 2 * i;
  float a = p[0], b = p[1];
  float c = cosb[t * 32 + i], sn = sinb[t * 32 + i];
  p[0] = a * c - b * sn;
  p[1] = a * sn + b * c;
}

// ---------------- tiled flash attention: block = (qtile64, h, b) -------------
__global__ __launch_bounds__(256) void attn_tile_k(const float* __restrict__ qkv,
                                                   bf16s* __restrict__ y) {
  __shared__ float Qs[64][64];
  __shared__ float Ks[64][65];
  __shared__ float Vs[64][64];
  __shared__ bf16s Ps[64][64];
  int qt = blockIdx.x, h = blockIdx.y, b = blockIdx.z;
  int tid = threadIdx.x, wv = tid >> 6, lane = tid & 63;
  int hkv = h >> 2;
  {
    int r = tid >> 2, u0 = (tid & 3) * 16;
    const float* src = qkv + ((size_t)(b*Tt + qt*64 + r)) * QKVD + h*HD + u0;
    #pragma unroll
    for (int j = 0; j < 4; j++)
      *(float4*)&Qs[r][u0 + j*4] = *(const float4*)(src + j*4);
  }
  float o[16], mr[16], lr[16], corr[16];
  #pragma unroll
  for (int i = 0; i < 16; i++) { o[i] = 0.f; mr[i] = -3e38f; lr[i] = 0.f; }
  for (int kt = 0; kt <= qt; kt++) {
    __syncthreads();
    {
      int r = tid >> 2, u0 = (tid & 3) * 16;
      const float* kr = qkv + ((size_t)(b*Tt + kt*64 + r)) * QKVD + Hh*HD + hkv*HD + u0;
      const float* vr = kr + KVH*HD;
      #pragma unroll
      for (int j = 0; j < 4; j++) {
        float4 f = *(const float4*)(kr + j*4);
        Ks[r][u0 + j*4 + 0] = f.x; Ks[r][u0 + j*4 + 1] = f.y;
        Ks[r][u0 + j*4 + 2] = f.z; Ks[r][u0 + j*4 + 3] = f.w;
        *(float4*)&Vs[r][u0 + j*4] = *(const float4*)(vr + j*4);
      }
    }
    __syncthreads();
    #pragma unroll
    for (int i = 0; i < 16; i++) {
      int q = wv*16 + i;
      float s = 0.f;
      for (int u = 0; u < 64; u++) s = fmaf(Qs[q][u], Ks[lane][u], s);
      s *= 0.125f;
      if (kt*64 + lane > qt*64 + q) s = -3e38f;
      float m = s;
      #pragma unroll
      for (int off = 32; off; off >>= 1) m = fmaxf(m, __shfl_xor(m, off, 64));
      float mnew = fmaxf(mr[i], m);
      float p = __expf(s - mnew);
      float rs = p;
      #pragma unroll
      for (int off = 32; off; off >>= 1) rs += __shfl_xor(rs, off, 64);
      float c = __expf(mr[i] - mnew);
      lr[i] = lr[i]*c + rs;
      mr[i] = mnew; corr[i] = c;
      Ps[q][lane] = f2bf(p);
    }
    #pragma unroll
    for (int i = 0; i < 16; i++) {
      int q = wv*16 + i;
      float a2 = 0.f;
      for (int u = 0; u < 64; u++) a2 = fmaf(bf2f(Ps[q][u]), Vs[u][lane], a2);
      o[i] = o[i]*corr[i] + a2;
    }
  }
  #pragma unroll
  for (int i = 0; i < 16; i++) {
    int q = wv*16 + i;
    size_t n = (size_t)b*Tt + qt*64 + q;
    y[n*Dd + h*HD + lane] = f2bf(o[i] / lr[i]);
  }
}

// ---------------- router ----------------
__global__ __launch_bounds__(64) void route_k(const float* __restrict__ xn,
    const float* __restrict__ gw, float* tp, float* prio, int* eids, float* scal) {
  int n = blockIdx.x, lane = threadIdx.x;
  float acc[8] = {};
  for (int d = lane; d < Dd; d += 64) {
    float xd = xn[(size_t)n * Dd + d];
    #pragma unroll
    for (int e = 0; e < 8; e++) acc[e] = fmaf(xd, gw[d * 8 + e], acc[e]);
  }
  #pragma unroll
  for (int e = 0; e < 8; e++)
    for (int o = 32; o > 0; o >>= 1) acc[e] += __shfl_down(acc[e], o, 64);
  if (lane == 0) {
    float l[8];
    #pragma unroll
    for (int e = 0; e < 8; e++) l[e] = acc[e];
    int i0 = 0;
    for (int e = 1; e < 8; e++) if (l[e] > l[i0]) i0 = e;
    int i1 = -1;
    for (int e = 0; e < 8; e++) {
      if (e == i0) continue;
      if (i1 < 0 || l[e] > l[i1]) i1 = e;
    }
    float v0 = l[i0], v1 = l[i1];
    float ex1 = __expf(v1 - v0);
    float p0 = 1.f / (1.f + ex1);
    float p1 = ex1 / (1.f + ex1);
    float m = v0, se = 0.f;
    float rp[8];
    #pragma unroll
    for (int e = 0; e < 8; e++) { rp[e] = __expf(l[e] - m); se += rp[e]; }
    float invse = 1.f / se;
    #pragma unroll
    for (int e = 0; e < 8; e++) atomicAdd(&scal[e], rp[e] * invse);
    atomicAdd(&scal[8 + i0], p0);
    atomicAdd(&scal[8 + i1], p1);
    float zl = m + logf(se);
    atomicAdd(&scal[16], zl * zl);
    eids[n*2] = i0; eids[n*2+1] = i1;
    prio[n*2] = v0; prio[n*2+1] = v1;
    tp[n*2] = p0;   tp[n*2+1] = p1;
  }
}

// ---------------- stable rank (lexsort equivalent) ----------------
__global__ void rank_k(const int* __restrict__ eids, const float* __restrict__ prio,
                       int* rowl) {
  int i = blockIdx.x * 256 + threadIdx.x;
  if (i >= NK) return;
  int e = eids[i];
  float p = prio[i];
  int r = 0;
  for (int j = 0; j < NK; j++) {
    if (eids[j] == e) {
      float pj = prio[j];
      if (pj > p || (pj == p && j < i)) r++;
    }
  }
  if (r < CAP) rowl[e * CAP + r] = i;
}

// ---------------- aux loss ----------------
__global__ void aux_k(const float* __restrict__ scal, float* out_aux) {
  if (threadIdx.x == 0 && blockIdx.x == 0) {
    float bal = 0.f;
    for (int e = 0; e < 8; e++)
      bal += (scal[e] / (float)NTOK) * (scal[8 + e] / (float)NTOK);
    out_aux[0] = AUXW * bal * (float)Ee + ZW * (scal[16] / (float)NTOK);
  }
}

// ---------------- gather rows into capacity layout (bf16) --------------------
__global__ void gather_k(const bf16s* __restrict__ xnb, const int* __restrict__ rowl,
                         bf16s* __restrict__ xg) {
  int idx = blockIdx.x * 256 + threadIdx.x;
  if (idx >= Ee*CAP*(Dd/4)) return;
  int rowi = idx / (Dd/4);
  int c4 = idx % (Dd/4);
  int it = rowl[rowi];
  s4 v = {};
  if (it >= 0) v = ((const s4*)xnb)[(size_t)(it >> 1) * (Dd/4) + c4];
  ((s4*)xg)[idx] = v;
}

// ---------------- seq prefill: mediator + zeros ------------------------------
__global__ void seqfill_k(const float* __restrict__ med, float* __restrict__ seq) {
  int idx = blockIdx.x * 256 + threadIdx.x;
  if (idx >= NTOK*3*(Dd/4)) return;
  int c4 = idx % (Dd/4);
  int s = (idx / (Dd/4)) % 3;
  float4 v = make_float4(0.f, 0.f, 0.f, 0.f);
  if (s == 0) v = ((const float4*)med)[c4];
  ((float4*)seq)[idx] = v;
}

// ---------------- collab attention (bf16 in/out, f32 math) ------------------
__global__ __launch_bounds__(256) void collab_attn_k(const bf16s* __restrict__ q,
    const bf16s* __restrict__ k, const bf16s* __restrict__ v, bf16s* __restrict__ o) {
  int n = blockIdx.x, tid = threadIdx.x;
  int h = tid >> 6, lane = tid & 63;
  __shared__ float s[4][9];
  size_t base = (size_t)n * 3 * Dd;
  #pragma unroll
  for (int i = 0; i < 3; i++)
    #pragma unroll
    for (int j = 0; j < 3; j++) {
      float d = 0.f;
      #pragma unroll
      for (int uu = 0; uu < 4; uu++) {
        int u = lane + uu*64;
        d = fmaf(bf2f(q[base + i*Dd + h*256 + u]), bf2f(k[base + j*Dd + h*256 + u]), d);
      }
      #pragma unroll
      for (int off = 32; off; off >>= 1) d += __shfl_xor(d, off, 64);
      if (lane == 0) s[h][i*3 + j] = d * 0.0625f;
    }
  __syncthreads();
  #pragma unroll
  for (int i = 0; i < 3; i++) {
    float s0 = s[h][i*3+0], s1 = s[h][i*3+1], s2 = s[h][i*3+2];
    float m = fmaxf(s0, fmaxf(s1, s2));
    float e0 = __expf(s0 - m), e1 = __expf(s1 - m), e2 = __expf(s2 - m);
    float inv = 1.f / (e0 + e1 + e2);
    e0 *= inv; e1 *= inv; e2 *= inv;
    #pragma unroll
    for (int dd = 0; dd < 4; dd++) {
      int u = lane + dd*64;
      float ov = e0 * bf2f(v[base + 0*Dd + h*256 + u])
               + e1 * bf2f(v[base + 1*Dd + h*256 + u])
               + e2 * bf2f(v[base + 2*Dd + h*256 + u]);
      o[base + i*Dd + h*256 + u] = f2bf(ov);
    }
  }
}

// ---------------- gated fusion (seq f32 -> fused bf16) -----------------------
__global__ __launch_bounds__(256) void fusion_k(const float* __restrict__ seq,
    const float* __restrict__ tp, const float* __restrict__ fg_w,
    const float* __restrict__ fg_b, bf16s* __restrict__ fused) {
  __shared__ float red[256];
  int n = blockIdx.x, tid = threadIdx.x;
  const float* med = seq + (size_t)n * 3 * Dd;
  const float* ex0 = med + Dd;
  const float* ex1 = med + 2*Dd;
  float4 m4 = ((const float4*)med)[tid];
  float4 w4 = ((const float4*)fg_w)[tid];
  float part = m4.x*w4.x + m4.y*w4.y + m4.z*w4.z + m4.w*w4.w;
  float dot = blockReduceSum256(part, red);
  float g = 1.f / (1.f + __expf(-(dot + fg_b[0])));
  float p0 = tp[n*2], p1 = tp[n*2+1];
  float4 e0 = ((const float4*)ex0)[tid];
  float4 e1 = ((const float4*)ex1)[tid];
  s4 r;
  r[0] = f2bf(g*m4.x + (1.f-g)*(p0*e0.x + p1*e1.x));
  r[1] = f2bf(g*m4.y + (1.f-g)*(p0*e0.y + p1*e1.y));
  r[2] = f2bf(g*m4.z + (1.f-g)*(p0*e0.z + p1*e1.z));
  r[3] = f2bf(g*m4.w + (1.f-g)*(p0*e0.w + p1*e1.w));
  ((s4*)fused)[(size_t)n*256 + tid] = r;
}

// ---------------- host launch ----------------
extern "C" void kernel_launch(void* const* d_in, const int* in_sizes, int n_in,
                              void* d_out, int out_size, void* d_ws, size_t ws_size,
                              hipStream_t stream) {
  const float* x_in   = (const float*)d_in[0];
  const float* fcos   = (const float*)d_in[1];
  const float* fsin   = (const float*)d_in[2];
  const float* ln1_w  = (const float*)d_in[3];
  const float* ln2_w  = (const float*)d_in[4];
  const float* w_qkv  = (const float*)d_in[5];
  const float* w_o    = (const float*)d_in[6];
  const float* gate_w = (const float*)d_in[7];
  const float* e_w13  = (const float*)d_in[8];
  const float* e_w2   = (const float*)d_in[9];
  const float* medi   = (const float*)d_in[10];
  const float* mwq    = (const float*)d_in[11];
  const float* mwk    = (const float*)d_in[12];
  const float* mwv    = (const float*)d_in[13];
  const float* mbq    = (const float*)d_in[14];
  const float* mbk    = (const float*)d_in[15];
  const float* mbv    = (const float*)d_in[16];
  const float* mwo    = (const float*)d_in[17];
  const float* mbo    = (const float*)d_in[18];
  const float* cn1_w  = (const float*)d_in[19];
  const float* cn2_w  = (const float*)d_in[20];
  const float* cf1_w  = (const float*)d_in[21];
  const float* cf2_w  = (const float*)d_in[22];
  const float* fg_w   = (const float*)d_in[23];
  const float* fg_b   = (const float*)d_in[24];
  const float* moe_ow = (const float*)d_in[25];

  char* ws = (char*)d_ws;
  bf16s* w13t  = (bf16s*)(ws + B_W13T);
  bf16s* w2t   = (bf16s*)(ws + B_W2T);
  bf16s* wqkvt = (bf16s*)(ws + B_WQKVT);
  bf16s* wot   = (bf16s*)(ws + B_WOT);
  bf16s* mwqt  = (bf16s*)(ws + B_MWQT);
  bf16s* mwkt  = (bf16s*)(ws + B_MWKT);
  bf16s* mwvt  = (bf16s*)(ws + B_MWVT);
  bf16s* mwot  = (bf16s*)(ws + B_MWOT);
  bf16s* cf1t  = (bf16s*)(ws + B_CF1T);
  bf16s* cf2t  = (bf16s*)(ws + B_CF2T);
  bf16s* moet  = (bf16s*)(ws + B_MOET);
  float* x1    = (float*)(ws + B_X1);
  float* xn    = (float*)(ws + B_XN);
  bf16s* xnb   = (bf16s*)(ws + B_XNB);
  float* seq   = (float*)(ws + B_SEQ);
  float* tp    = (float*)(ws + B_TP);
  float* prio  = (float*)(ws + B_PRIO);
  float* scal  = (float*)(ws + B_SCAL);
  int*   eids  = (int*)(ws + B_EIDS);
  int*   rowl  = (int*)(ws + B_ROWL);
  char*  big   = ws + B_BIG;
  bf16s* hnb   = (bf16s*)(big + BG_HNB);
  float* qkvb  = (float*)(big + BG_QKVB);
  bf16s* yb    = (bf16s*)(big + BG_YB);
  bf16s* xg    = (bf16s*)(big + BG_XG);
  bf16s* actb  = (bf16s*)(big + BG_ACTB);
  bf16s* nrmb  = (bf16s*)(big + BG_NRM);
  bf16s* cqb   = (bf16s*)(big + BG_CQ);
  bf16s* ckb   = (bf16s*)(big + BG_CK);
  bf16s* cvb   = (bf16s*)(big + BG_CV);
  bf16s* atnob = (bf16s*)(big + BG_ATNO);
  bf16s* ffhb  = (bf16s*)(big + BG_FFH);
  bf16s* fuseb = (bf16s*)(big + BG_FUSE);

  float* out_x   = (float*)d_out;
  float* out_aux = out_x + (size_t)NTOK * Dd;

  dim3 blk(256);

  init_k<<<dim3(32), blk, 0, stream>>>(scal, rowl);

  // weight transposes (f32 [K][N] -> bf16 [N][K])
  transpose_cast_k<<<dim3(QKVD/32, Dd/32), blk, 0, stream>>>(w_qkv, wqkvt, Dd, QKVD, 0, 0);
  transpose_cast_k<<<dim3(Dd/32, Dd/32), blk, 0, stream>>>(w_o,  wot,  Dd, Dd, 0, 0);
  transpose_cast_k<<<dim3(Dd/32, Dd/32), blk, 0, stream>>>(mwq,  mwqt, Dd, Dd, 0, 0);
  transpose_cast_k<<<dim3(Dd/32, Dd/32), blk, 0, stream>>>(mwk,  mwkt, Dd, Dd, 0, 0);
  transpose_cast_k<<<dim3(Dd/32, Dd/32), blk, 0, stream>>>(mwv,  mwvt, Dd, Dd, 0, 0);
  transpose_cast_k<<<dim3(Dd/32, Dd/32), blk, 0, stream>>>(mwo,  mwot, Dd, Dd, 0, 0);
  transpose_cast_k<<<dim3(Dd/32, Dd/32), blk, 0, stream>>>(cf1_w, cf1t, Dd, Dd, 0, 0);
  transpose_cast_k<<<dim3(Dd/32, Dd/32), blk, 0, stream>>>(cf2_w, cf2t, Dd, Dd, 0, 0);
  transpose_cast_k<<<dim3(Dd/32, Dd/32), blk, 0, stream>>>(moe_ow, moet, Dd, Dd, 0, 0);
  transpose_cast_k<<<dim3(2*HID/32, Dd/32, Ee), blk, 0, stream>>>(
      e_w13, w13t, Dd, 2*HID, (size_t)Dd*2*HID, (size_t)2*HID*Dd);
  transpose_cast_k<<<dim3(Dd/32, HID/32, Ee), blk, 0, stream>>>(
      e_w2, w2t, HID, Dd, (size_t)HID*Dd, (size_t)Dd*HID);

  // attention block
  rmsnorm_k<<<dim3(NTOK), blk, 0, stream>>>(x_in, ln1_w, (float*)nullptr, hnb);
  gemm_bt<false,false><<<dim3(QKVD/128, NTOK/128), blk, 0, stream>>>(
      hnb, wqkvt, nullptr, nullptr, qkvb, NTOK, QKVD, Dd);
  rope_k<<<dim3((NTOK*20*32)/256), blk, 0, stream>>>(qkvb, fcos, fsin);
  attn_tile_k<<<dim3(Tt/64, Hh, Bb), blk, 0, stream>>>(qkvb, yb);
  gemm_bt<false,false><<<dim3(Dd/128, NTOK/128), blk, 0, stream>>>(
      yb, wot, nullptr, x_in, x1, NTOK, Dd, Dd);

  // routing
  rmsnorm_k<<<dim3(NTOK), blk, 0, stream>>>(x1, ln2_w, xn, xnb);
  route_k<<<dim3(NTOK), dim3(64), 0, stream>>>(xn, gate_w, tp, prio, eids, scal);
  rank_k<<<dim3(NK/256), blk, 0, stream>>>(eids, prio, rowl);
  aux_k<<<dim3(1), dim3(64), 0, stream>>>(scal, out_aux);

  // expert FFN
  gather_k<<<dim3(Ee*CAP*(Dd/4)/256), blk, 0, stream>>>(xnb, rowl, xg);
  seqfill_k<<<dim3(NTOK*3*(Dd/4)/256), blk, 0, stream>>>(medi, seq);
  gemm_w13<<<dim3(HID/64, CAP/128, Ee), blk, 0, stream>>>(xg, w13t, rowl, actb);
  gemm_w2<<<dim3(Dd/128, CAP/128, Ee), blk, 0, stream>>>(actb, w2t, xn, rowl, seq);

  // collab transformer (2 rounds)
  for (int r = 0; r < 2; r++) {
    rmsnorm_k<<<dim3(NTOK*3), blk, 0, stream>>>(seq, cn1_w, (float*)nullptr, nrmb);
    gemm_bt<true,false><<<dim3(Dd/128, NTOK*3/128), blk, 0, stream>>>(
        nrmb, mwqt, mbq, nullptr, cqb, NTOK*3, Dd, Dd);
    gemm_bt<true,false><<<dim3(Dd/128, NTOK*3/128), blk, 0, stream>>>(
        nrmb, mwkt, mbk, nullptr, ckb, NTOK*3, Dd, Dd);
    gemm_bt<true,false><<<dim3(Dd/128, NTOK*3/128), blk, 0, stream>>>(
        nrmb, mwvt, mbv, nullptr, cvb, NTOK*3, Dd, Dd);
    collab_attn_k<<<dim3(NTOK), blk, 0, stream>>>(cqb, ckb, cvb, atnob);
    gemm_bt<false,false><<<dim3(Dd/128, NTOK*3/128), blk, 0, stream>>>(
        atnob, mwot, mbo, seq, seq, NTOK*3, Dd, Dd);
    rmsnorm_k<<<dim3(NTOK*3), blk, 0, stream>>>(seq, cn2_w, (float*)nullptr, nrmb);
    gemm_bt<true,true><<<dim3(Dd/128, NTOK*3/128), blk, 0, stream>>>(
        nrmb, cf1t, nullptr, nullptr, ffhb, NTOK*3, Dd, Dd);
    gemm_bt<false,false><<<dim3(Dd/128, NTOK*3/128), blk, 0, stream>>>(
        ffhb, cf2t, nullptr, seq, seq, NTOK*3, Dd, Dd);
  }

  // fusion + final projection
  fusion_k<<<dim3(NTOK), blk, 0, stream>>>(seq, tp, fg_w, fg_b, fuseb);
  gemm_bt<false,false><<<dim3(Dd/128, NTOK/128), blk, 0, stream>>>(
      fuseb, moet, nullptr, x1, out_x, NTOK, Dd, Dd);
}

// Round 3
// 2115.026 us; speedup vs baseline: 2.7669x; 1.4989x over previous
//
#include <hip/hip_runtime.h>

// ---------------- problem constants ----------------
constexpr int Bb   = 2;
constexpr int Tt   = 1024;
constexpr int Dd   = 1024;
constexpr int Hh   = 16;
constexpr int KVH  = 4;
constexpr int HD   = 64;
constexpr int NTOK = Bb*Tt;              // 2048
constexpr int QKVD = (Hh+2*KVH)*HD;      // 1536
constexpr int Ee   = 8;
constexpr int HID  = 2816;
constexpr int NK   = NTOK*2;             // 4096
constexpr int CAP  = 1024;
constexpr float EPS  = 1e-6f;
constexpr float AUXW = 0.01f;
constexpr float ZW   = 0.001f;

typedef short bf16s;
typedef __attribute__((ext_vector_type(8))) short s8;
typedef __attribute__((ext_vector_type(4))) short s4;
typedef __attribute__((ext_vector_type(4))) float f4;

__device__ __forceinline__ short f2bf(float f) {
  union { float f; unsigned u; } v; v.f = f;
  unsigned r = (v.u + 0x7fffu + ((v.u >> 16) & 1u)) >> 16;
  return (short)r;
}
__device__ __forceinline__ float bf2f(short s) {
  union { unsigned u; float f; } v; v.u = ((unsigned)(unsigned short)s) << 16;
  return v.f;
}
__device__ __forceinline__ void gload16(const void* g, void* l) {
  __builtin_amdgcn_global_load_lds(
      (const __attribute__((address_space(1))) void*)g,
      (__attribute__((address_space(3))) void*)l, 16, 0, 0);
}

// ---------------- ws layout (byte offsets) ----------------
constexpr size_t B_W13T = 0;
constexpr size_t S_W13T = (size_t)Ee*2*HID*Dd*2;          // 92,274,688
constexpr size_t B_W2T  = B_W13T + S_W13T;
constexpr size_t S_W2T  = (size_t)Ee*Dd*HID*2;            // 46,137,344
constexpr size_t B_WQKVT= B_W2T + S_W2T;
constexpr size_t S_WQKVT= (size_t)QKVD*Dd*2;
constexpr size_t B_WOT  = B_WQKVT + S_WQKVT;
constexpr size_t S_SQ   = (size_t)Dd*Dd*2;
constexpr size_t B_MWQT = B_WOT + S_SQ;
constexpr size_t B_MWKT = B_MWQT + S_SQ;
constexpr size_t B_MWVT = B_MWKT + S_SQ;
constexpr size_t B_MWOT = B_MWVT + S_SQ;
constexpr size_t B_CF1T = B_MWOT + S_SQ;
constexpr size_t B_CF2T = B_CF1T + S_SQ;
constexpr size_t B_MOET = B_CF2T + S_SQ;
constexpr size_t B_X1   = B_MOET + S_SQ;
constexpr size_t B_XN   = B_X1 + (size_t)NTOK*Dd*4;
constexpr size_t B_XNB  = B_XN + (size_t)NTOK*Dd*4;
constexpr size_t B_SEQ  = B_XNB + (size_t)NTOK*Dd*2;
constexpr size_t B_TP   = B_SEQ + (size_t)NTOK*3*Dd*4;
constexpr size_t B_PRIO = B_TP + (size_t)NK*4;
constexpr size_t B_SCAL = B_PRIO + (size_t)NK*4;
constexpr size_t B_EIDS = B_SCAL + 256;
constexpr size_t B_ROWL = B_EIDS + (size_t)NK*4;
constexpr size_t B_BIG  = B_ROWL + (size_t)Ee*CAP*4;
// BIG overlays (phase-disjoint)
constexpr size_t BG_HNB  = 0;                              // bf16 4 MB
constexpr size_t BG_QKVB = (size_t)NTOK*Dd*2;              // f32 12.58 MB
constexpr size_t BG_QK16 = BG_QKVB + (size_t)NTOK*QKVD*4;  // bf16 6.29 MB
constexpr size_t BG_YB   = BG_QK16 + (size_t)NTOK*QKVD*2;  // bf16 4 MB
constexpr size_t BG_XG   = 0;
constexpr size_t BG_ACTB = (size_t)Ee*CAP*Dd*2;            // 16.78 MB
constexpr size_t BG_NRM  = 0;
constexpr size_t BG_CQ   = (size_t)NTOK*3*Dd*2;            // 12.58 MB
constexpr size_t BG_CK   = BG_CQ*2;
constexpr size_t BG_CV   = BG_CQ*3;
constexpr size_t BG_ATNO = BG_CQ*4;
constexpr size_t BG_FFH  = BG_CQ;     // reuse cq (dead after collab_attn)
constexpr size_t BG_FUSE = BG_CQ*2;   // reuse ck

// ---------------- helpers ----------------
__device__ __forceinline__ float blockReduceSum256(float v, float* red) {
  int tid = threadIdx.x;
  red[tid] = v; __syncthreads();
  for (int o = 128; o > 0; o >>= 1) {
    if (tid < o) red[tid] += red[tid + o];
    __syncthreads();
  }
  float r = red[0]; __syncthreads();
  return r;
}

// ---------------- init ----------------
__global__ void init_k(float* scal, int* rowl) {
  int i = blockIdx.x * 256 + threadIdx.x;
  if (i < 32) scal[i] = 0.f;
  if (i < Ee*CAP) rowl[i] = -1;
}

// ---------------- transpose+cast: src f32 [K][N] -> dst bf16 [N][K] ----------
__global__ __launch_bounds__(256) void transpose_cast_k(
    const float* __restrict__ src, bf16s* __restrict__ dst,
    int K, int N, size_t sstride, size_t dstride) {
  __shared__ float t[32][33];
  src += blockIdx.z * sstride; dst += blockIdx.z * dstride;
  int n0 = blockIdx.x * 32, k0 = blockIdx.y * 32;
  int tx = threadIdx.x & 31, ty = threadIdx.x >> 5;
  #pragma unroll
  for (int p = 0; p < 4; p++)
    t[ty + p*8][tx] = src[(size_t)(k0 + ty + p*8) * N + n0 + tx];
  __syncthreads();
  #pragma unroll
  for (int p = 0; p < 4; p++)
    dst[(size_t)(n0 + ty + p*8) * K + k0 + tx] = f2bf(t[tx][ty + p*8]);
}

// ---------------- rmsnorm (f32 in; optional f32 out + bf16 out) --------------
__global__ __launch_bounds__(256) void rmsnorm_k(const float* __restrict__ in,
    const float* __restrict__ w, float* __restrict__ outf, bf16s* __restrict__ outb) {
  __shared__ float red[256];
  int r = blockIdx.x, tid = threadIdx.x;
  float4 v = ((const float4*)(in + (size_t)r * Dd))[tid];
  float s = v.x*v.x + v.y*v.y + v.z*v.z + v.w*v.w;
  float tot = blockReduceSum256(s, red);
  float scale = rsqrtf(tot / (float)Dd + EPS);
  float4 wv = ((const float4*)w)[tid];
  float o0 = v.x*scale*wv.x, o1 = v.y*scale*wv.y, o2 = v.z*scale*wv.z, o3 = v.w*scale*wv.w;
  if (outf) ((float4*)(outf + (size_t)r * Dd))[tid] = make_float4(o0, o1, o2, o3);
  if (outb) {
    s4 p; p[0] = f2bf(o0); p[1] = f2bf(o1); p[2] = f2bf(o2); p[3] = f2bf(o3);
    ((s4*)(outb + (size_t)r * Dd))[tid] = p;
  }
}

// ---------------- MFMA GEMM: C = [res +] act(A @ Bt^T [+ bias]) --------------
// A: [M][K] bf16, Bt: [N][K] bf16. 128x128 tile, BK=32, 4 waves.
template<bool OUTBF, bool GELU>
__global__ __launch_bounds__(256) void gemm_bt(
    const bf16s* __restrict__ A, const bf16s* __restrict__ Bt,
    const float* __restrict__ bias, const float* __restrict__ res,
    void* __restrict__ Cout, int M, int N, int K) {
  __shared__ bf16s As[128*32];
  __shared__ bf16s Bs[128*32];
  const int tid = threadIdx.x, w = tid >> 6, lane = tid & 63;
  const int row0 = blockIdx.y * 128, col0 = blockIdx.x * 128;
  const int wm = w >> 1, wn = w & 1;
  f4 acc[4][4] = {};
  const int sr = lane >> 2, sc = (lane & 3) * 8;
  for (int k0 = 0; k0 < K; k0 += 32) {
    #pragma unroll
    for (int i = 0; i < 2; i++) {
      int seg = w*2 + i;
      gload16(A  + (size_t)(row0 + seg*16 + sr) * K + k0 + sc, &As[seg*512]);
      gload16(Bt + (size_t)(col0 + seg*16 + sr) * K + k0 + sc, &Bs[seg*512]);
    }
    __syncthreads();
    const int fr = lane & 15, kb = lane >> 4;
    s8 a[4], b[4];
    #pragma unroll
    for (int mi = 0; mi < 4; mi++) a[mi] = *(const s8*)&As[(wm*64 + mi*16 + fr)*32 + kb*8];
    #pragma unroll
    for (int ni = 0; ni < 4; ni++) b[ni] = *(const s8*)&Bs[(wn*64 + ni*16 + fr)*32 + kb*8];
    #pragma unroll
    for (int mi = 0; mi < 4; mi++)
      #pragma unroll
      for (int ni = 0; ni < 4; ni++)
        acc[mi][ni] = __builtin_amdgcn_mfma_f32_16x16x32_bf16(a[mi], b[ni], acc[mi][ni], 0, 0, 0);
    __syncthreads();
  }
  const int cr = (lane >> 4) * 4, cc = lane & 15;
  #pragma unroll
  for (int mi = 0; mi < 4; mi++) {
    #pragma unroll
    for (int ni = 0; ni < 4; ni++) {
      int col = col0 + wn*64 + ni*16 + cc;
      float bv = bias ? bias[col] : 0.f;
      #pragma unroll
      for (int q = 0; q < 4; q++) {
        int row = row0 + wm*64 + mi*16 + cr + q;
        float v = acc[mi][ni][q] + bv;
        if (GELU) v = 0.5f * v * (1.f + erff(v * 0.70710678118f));
        if (res) v += res[(size_t)row * N + col];
        if (OUTBF) ((bf16s*)Cout)[(size_t)row * N + col] = f2bf(v);
        else       ((float*)Cout)[(size_t)row * N + col] = v;
      }
    }
  }
}

// ---------------- expert w13 fused (g,u) GEMM: actb = silu(2g)*(2u) ----------
__global__ __launch_bounds__(256) void gemm_w13(
    const bf16s* __restrict__ xg, const bf16s* __restrict__ w13t,
    const int* __restrict__ rowl, bf16s* __restrict__ actb) {
  const int e = blockIdx.z;
  const int row0 = blockIdx.y * 128, col0 = blockIdx.x * 64;
  if (rowl[e*CAP + row0] < 0) return;
  __shared__ bf16s As[128*32];
  __shared__ bf16s Bgs[64*32];
  __shared__ bf16s Bus[64*32];
  const int tid = threadIdx.x, w = tid >> 6, lane = tid & 63;
  const int wm = w >> 1, wn = w & 1;
  const bf16s* Ab = xg + (size_t)e * CAP * Dd;
  const bf16s* Wg = w13t + (size_t)e * (2*HID) * Dd + (size_t)col0 * Dd;
  const bf16s* Wu = Wg + (size_t)HID * Dd;
  f4 ag[4][2] = {}, au[4][2] = {};
  const int sr = lane >> 2, sc = (lane & 3) * 8;
  for (int k0 = 0; k0 < Dd; k0 += 32) {
    #pragma unroll
    for (int i = 0; i < 2; i++) {
      int seg = w*2 + i;
      gload16(Ab + (size_t)(row0 + seg*16 + sr) * Dd + k0 + sc, &As[seg*512]);
    }
    gload16(Wg + (size_t)(w*16 + sr) * Dd + k0 + sc, &Bgs[w*512]);
    gload16(Wu + (size_t)(w*16 + sr) * Dd + k0 + sc, &Bus[w*512]);
    __syncthreads();
    const int fr = lane & 15, kb = lane >> 4;
    s8 a[4], bg[2], bu[2];
    #pragma unroll
    for (int mi = 0; mi < 4; mi++) a[mi] = *(const s8*)&As[(wm*64 + mi*16 + fr)*32 + kb*8];
    #pragma unroll
    for (int ni = 0; ni < 2; ni++) {
      bg[ni] = *(const s8*)&Bgs[(wn*32 + ni*16 + fr)*32 + kb*8];
      bu[ni] = *(const s8*)&Bus[(wn*32 + ni*16 + fr)*32 + kb*8];
    }
    #pragma unroll
    for (int mi = 0; mi < 4; mi++)
      #pragma unroll
      for (int ni = 0; ni < 2; ni++) {
        ag[mi][ni] = __builtin_amdgcn_mfma_f32_16x16x32_bf16(a[mi], bg[ni], ag[mi][ni], 0, 0, 0);
        au[mi][ni] = __builtin_amdgcn_mfma_f32_16x16x32_bf16(a[mi], bu[ni], au[mi][ni], 0, 0, 0);
      }
    __syncthreads();
  }
  const int cr = (lane >> 4) * 4, cc = lane & 15;
  #pragma unroll
  for (int mi = 0; mi < 4; mi++)
    #pragma unroll
    for (int ni = 0; ni < 2; ni++)
      #pragma unroll
      for (int q = 0; q < 4; q++) {
        int row = row0 + wm*64 + mi*16 + cr + q;
        int col = col0 + wn*32 + ni*16 + cc;
        float g = 2.f * ag[mi][ni][q], u = 2.f * au[mi][ni][q];
        float sv = g / (1.f + __expf(-g)) * u;
        actb[((size_t)e*CAP + row) * HID + col] = f2bf(sv);
      }
}

// ---------------- expert w2 GEMM with scatter into seq -----------------------
__global__ __launch_bounds__(256) void gemm_w2(
    const bf16s* __restrict__ actb, const bf16s* __restrict__ w2t,
    const float* __restrict__ xn, const int* __restrict__ rowl,
    float* __restrict__ seq) {
  const int e = blockIdx.z;
  const int row0 = blockIdx.y * 128, col0 = blockIdx.x * 128;
  if (rowl[e*CAP + row0] < 0) return;
  __shared__ bf16s As[128*32];
  __shared__ bf16s Bs[128*32];
  const int tid = threadIdx.x, w = tid >> 6, lane = tid & 63;
  const int wm = w >> 1, wn = w & 1;
  const bf16s* Ab = actb + (size_t)e * CAP * HID;
  const bf16s* Bt = w2t + (size_t)e * Dd * HID;
  f4 acc[4][4] = {};
  const int sr = lane >> 2, sc = (lane & 3) * 8;
  for (int k0 = 0; k0 < HID; k0 += 32) {
    #pragma unroll
    for (int i = 0; i < 2; i++) {
      int seg = w*2 + i;
      gload16(Ab + (size_t)(row0 + seg*16 + sr) * HID + k0 + sc, &As[seg*512]);
      gload16(Bt + (size_t)(col0 + seg*16 + sr) * HID + k0 + sc, &Bs[seg*512]);
    }
    __syncthreads();
    const int fr = lane & 15, kb = lane >> 4;
    s8 a[4], b[4];
    #pragma unroll
    for (int mi = 0; mi < 4; mi++) a[mi] = *(const s8*)&As[(wm*64 + mi*16 + fr)*32 + kb*8];
    #pragma unroll
    for (int ni = 0; ni < 4; ni++) b[ni] = *(const s8*)&Bs[(wn*64 + ni*16 + fr)*32 + kb*8];
    #pragma unroll
    for (int mi = 0; mi < 4; mi++)
      #pragma unroll
      for (int ni = 0; ni < 4; ni++)
        acc[mi][ni] = __builtin_amdgcn_mfma_f32_16x16x32_bf16(a[mi], b[ni], acc[mi][ni], 0, 0, 0);
    __syncthreads();
  }
  const int cr = (lane >> 4) * 4, cc = lane & 15;
  #pragma unroll
  for (int mi = 0; mi < 4; mi++)
    #pragma unroll
    for (int q = 0; q < 4; q++) {
      int row = row0 + wm*64 + mi*16 + cr + q;
      int it = rowl[e*CAP + row];
      if (it < 0) continue;
      int n = it >> 1, s = 1 + (it & 1);
      #pragma unroll
      for (int ni = 0; ni < 4; ni++) {
        int col = col0 + wn*64 + ni*16 + cc;
        seq[((size_t)n*3 + s) * Dd + col] = xn[(size_t)n * Dd + col] + acc[mi][ni][q];
      }
    }
}

// ---------------- RoPE + cast to bf16 (Q pre-scaled by 1/sqrt(HD)) ----------
__global__ __launch_bounds__(256) void rope_cast_k(const float* __restrict__ qkv,
    const float* __restrict__ cosb, const float* __restrict__ sinb,
    bf16s* __restrict__ out) {
  int idx = blockIdx.x * 256 + threadIdx.x;   // NTOK * 768 pairs
  if (idx >= NTOK * (QKVD/2)) return;
  int p = idx % (QKVD/2);
  int n = idx / (QKVD/2);
  int seg = p >> 5, i = p & 31;
  const float* src = qkv + (size_t)n * QKVD + p*2;
  float a = src[0], b = src[1];
  float r0, r1;
  if (seg < 20) {   // q heads (0..15) and k heads (16..19): rope
    int t = n & (Tt - 1);
    float c = cosb[t*32 + i], sn = sinb[t*32 + i];
    r0 = a*c - b*sn;
    r1 = a*sn + b*c;
    if (seg < 16) { r0 *= 0.125f; r1 *= 0.125f; }  // 1/sqrt(64) folded into Q
  } else {          // v heads: plain cast
    r0 = a; r1 = b;
  }
  unsigned w = (unsigned)(unsigned short)f2bf(r0) | ((unsigned)(unsigned short)f2bf(r1) << 16);
  ((unsigned*)out)[(size_t)n * (QKVD/2) + p] = w;
}

// ---------------- MFMA flash attention: block = (qtile64, h, b) --------------
// LDS tiles padded to stride 72 bf16 (144B): fragment reads 2 lanes/bank (free).
__global__ __launch_bounds__(256) void attn_mfma_k(const bf16s* __restrict__ qkv,
                                                   bf16s* __restrict__ y) {
  __shared__ bf16s Qs[64*72];
  __shared__ bf16s Ks[64*72];
  __shared__ bf16s Vt[64*72];
  __shared__ bf16s Ps[4][16*72];
  const int qt = blockIdx.x, h = blockIdx.y, b = blockIdx.z;
  const int tid = threadIdx.x, w = tid >> 6, lane = tid & 63;
  const int hkv = h >> 2;
  const bf16s* qb = qkv + (size_t)(b*Tt + qt*64) * QKVD + h*HD;
  const bf16s* kb = qkv + (size_t)(b*Tt) * QKVD + Hh*HD + hkv*HD;
  const bf16s* vb = kb + KVH*HD;
  // stage Q (64 rows x 64 bf16)
  #pragma unroll
  for (int c = 0; c < 2; c++) {
    int ch = tid + c*256;
    int r = ch >> 3, off = (ch & 7) * 8;
    *(s8*)&Qs[r*72 + off] = *(const s8*)(qb + (size_t)r * QKVD + off);
  }
  const int fr = lane & 15, kb4 = lane >> 4;
  const int rq = kb4 * 4;
  f4 oac[4] = {};
  float mr[4], lr[4];
  #pragma unroll
  for (int q = 0; q < 4; q++) { mr[q] = -3e30f; lr[q] = 0.f; }
  for (int kt = 0; kt <= qt; kt++) {
    __syncthreads();
    // stage K rows + V transposed
    #pragma unroll
    for (int c = 0; c < 2; c++) {
      int ch = tid + c*256;
      int r = ch >> 3, off = (ch & 7) * 8;
      *(s8*)&Ks[r*72 + off] = *(const s8*)(kb + (size_t)(kt*64 + r) * QKVD + off);
      s8 v = *(const s8*)(vb + (size_t)(kt*64 + r) * QKVD + off);
      #pragma unroll
      for (int j = 0; j < 8; j++) Vt[(off + j)*72 + r] = v[j];
    }
    __syncthreads();
    // S = Q K^T  (wave w: rows w*16..w*16+15)
    f4 sac[4] = {};
    s8 aq0 = *(const s8*)&Qs[(w*16 + fr)*72 + kb4*8];
    s8 aq1 = *(const s8*)&Qs[(w*16 + fr)*72 + 32 + kb4*8];
    #pragma unroll
    for (int ni = 0; ni < 4; ni++) {
      s8 bk0 = *(const s8*)&Ks[(ni*16 + fr)*72 + kb4*8];
      s8 bk1 = *(const s8*)&Ks[(ni*16 + fr)*72 + 32 + kb4*8];
      sac[ni] = __builtin_amdgcn_mfma_f32_16x16x32_bf16(aq0, bk0, sac[ni], 0, 0, 0);
      sac[ni] = __builtin_amdgcn_mfma_f32_16x16x32_bf16(aq1, bk1, sac[ni], 0, 0, 0);
    }
    // causal mask (diagonal tile only): col fr+16ni vs row w*16+rq+q
    if (kt == qt) {
      #pragma unroll
      for (int ni = 0; ni < 4; ni++)
        #pragma unroll
        for (int q = 0; q < 4; q++)
          if (fr + 16*ni > w*16 + rq + q) sac[ni][q] = -3e30f;
    }
    // online softmax on C-layout fragments
    float tm[4], rs[4], corr[4];
    #pragma unroll
    for (int q = 0; q < 4; q++)
      tm[q] = fmaxf(fmaxf(sac[0][q], sac[1][q]), fmaxf(sac[2][q], sac[3][q]));
    #pragma unroll
    for (int off = 1; off < 16; off <<= 1)
      #pragma unroll
      for (int q = 0; q < 4; q++) tm[q] = fmaxf(tm[q], __shfl_xor(tm[q], off, 64));
    #pragma unroll
    for (int q = 0; q < 4; q++) {
      float mnew = fmaxf(mr[q], tm[q]);
      corr[q] = __expf(mr[q] - mnew);
      mr[q] = mnew;
      rs[q] = 0.f;
    }
    #pragma unroll
    for (int ni = 0; ni < 4; ni++)
      #pragma unroll
      for (int q = 0; q < 4; q++) {
        float p = __expf(sac[ni][q] - mr[q]);
        sac[ni][q] = p;
        rs[q] += p;
      }
    #pragma unroll
    for (int off = 1; off < 16; off <<= 1)
      #pragma unroll
      for (int q = 0; q < 4; q++) rs[q] += __shfl_xor(rs[q], off, 64);
    #pragma unroll
    for (int q = 0; q < 4; q++) lr[q] = lr[q]*corr[q] + rs[q];
    #pragma unroll
    for (int ni = 0; ni < 4; ni++)
      #pragma unroll
      for (int q = 0; q < 4; q++) oac[ni][q] *= corr[q];
    // P: C-layout -> A-layout via per-wave LDS strip
    #pragma unroll
    for (int ni = 0; ni < 4; ni++)
      #pragma unroll
      for (int q = 0; q < 4; q++)
        Ps[w][(rq + q)*72 + fr + 16*ni] = f2bf(sac[ni][q]);
    __syncthreads();
    // O += P V  (B-operand = Vt rows)
    s8 ap0 = *(const s8*)&Ps[w][fr*72 + kb4*8];
    s8 ap1 = *(const s8*)&Ps[w][fr*72 + 32 + kb4*8];
    #pragma unroll
    for (int ni = 0; ni < 4; ni++) {
      s8 bv0 = *(const s8*)&Vt[(ni*16 + fr)*72 + kb4*8];
      s8 bv1 = *(const s8*)&Vt[(ni*16 + fr)*72 + 32 + kb4*8];
      oac[ni] = __builtin_amdgcn_mfma_f32_16x16x32_bf16(ap0, bv0, oac[ni], 0, 0, 0);
      oac[ni] = __builtin_amdgcn_mfma_f32_16x16x32_bf16(ap1, bv1, oac[ni], 0, 0, 0);
    }
  }
  // epilogue
  #pragma unroll
  for (int q = 0; q < 4; q++) {
    float inv = 1.f / lr[q];
    int row = qt*64 + w*16 + rq + q;
    #pragma unroll
    for (int ni = 0; ni < 4; ni++)
      y[((size_t)(b*Tt + row)) * Dd + h*HD + fr + 16*ni] = f2bf(oac[ni][q] * inv);
  }
}

// ---------------- router ----------------
__global__ __launch_bounds__(64) void route_k(const float* __restrict__ xn,
    const float* __restrict__ gw, float* tp, float* prio, int* eids, float* scal) {
  int n = blockIdx.x, lane = threadIdx.x;
  float acc[8] = {};
  for (int d = lane; d < Dd; d += 64) {
    float xd = xn[(size_t)n * Dd + d];
    #pragma unroll
    for (int e = 0; e < 8; e++) acc[e] = fmaf(xd, gw[d * 8 + e], acc[e]);
  }
  #pragma unroll
  for (int e = 0; e < 8; e++)
    for (int o = 32; o > 0; o >>= 1) acc[e] += __shfl_down(acc[e], o, 64);
  if (lane == 0) {
    float l[8];
    #pragma unroll
    for (int e = 0; e < 8; e++) l[e] = acc[e];
    int i0 = 0;
    for (int e = 1; e < 8; e++) if (l[e] > l[i0]) i0 = e;
    int i1 = -1;
    for (int e = 0; e < 8; e++) {
      if (e == i0) continue;
      if (i1 < 0 || l[e] > l[i1]) i1 = e;
    }
    float v0 = l[i0], v1 = l[i1];
    float ex1 = __expf(v1 - v0);
    float p0 = 1.f / (1.f + ex1);
    float p1 = ex1 / (1.f + ex1);
    float m = v0, se = 0.f;
    float rp[8];
    #pragma unroll
    for (int e = 0; e < 8; e++) { rp[e] = __expf(l[e] - m); se += rp[e]; }
    float invse = 1.f / se;
    #pragma unroll
    for (int e = 0; e < 8; e++) atomicAdd(&scal[e], rp[e] * invse);
    atomicAdd(&scal[8 + i0], p0);
    atomicAdd(&scal[8 + i1], p1);
    float zl = m + logf(se);
    atomicAdd(&scal[16], zl * zl);
    eids[n*2] = i0; eids[n*2+1] = i1;
    prio[n*2] = v0; prio[n*2+1] = v1;
    tp[n*2] = p0;   tp[n*2+1] = p1;
  }
}

// ---------------- stable rank (lexsort equivalent) ----------------
__global__ void rank_k(const int* __restrict__ eids, const float* __restrict__ prio,
                       int* rowl) {
  int i = blockIdx.x * 256 + threadIdx.x;
  if (i >= NK) return;
  int e = eids[i];
  float p = prio[i];
  int r = 0;
  for (int j = 0; j < NK; j++) {
    if (eids[j] == e) {
      float pj = prio[j];
      if (pj > p || (pj == p && j < i)) r++;
    }
  }
  if (r < CAP) rowl[e * CAP + r] = i;
}

// ---------------- aux loss ----------------
__global__ void aux_k(const float* __restrict__ scal, float* out_aux) {
  if (threadIdx.x == 0 && blockIdx.x == 0) {
    float bal = 0.f;
    for (int e = 0; e < 8; e++)
      bal += (scal[e] / (float)NTOK) * (scal[8 + e] / (float)NTOK);
    out_aux[0] = AUXW * bal * (float)Ee + ZW * (scal[16] / (float)NTOK);
  }
}

// ---------------- gather rows into capacity layout (bf16) --------------------
__global__ void gather_k(const bf16s* __restrict__ xnb, const int* __restrict__ rowl,
                         bf16s* __restrict__ xg) {
  int idx = blockIdx.x * 256 + threadIdx.x;
  if (idx >= Ee*CAP*(Dd/4)) return;
  int rowi = idx / (Dd/4);
  int c4 = idx % (Dd/4);
  int it = rowl[rowi];
  s4 v = {};
  if (it >= 0) v = ((const s4*)xnb)[(size_t)(it >> 1) * (Dd/4) + c4];
  ((s4*)xg)[idx] = v;
}

// ---------------- seq prefill: mediator + zeros ------------------------------
__global__ void seqfill_k(const float* __restrict__ med, float* __restrict__ seq) {
  int idx = blockIdx.x * 256 + threadIdx.x;
  if (idx >= NTOK*3*(Dd/4)) return;
  int c4 = idx % (Dd/4);
  int s = (idx / (Dd/4)) % 3;
  float4 v = make_float4(0.f, 0.f, 0.f, 0.f);
  if (s == 0) v = ((const float4*)med)[c4];
  ((float4*)seq)[idx] = v;
}

// ---------------- collab attention (bf16 in/out, f32 math) ------------------
__global__ __launch_bounds__(256) void collab_attn_k(const bf16s* __restrict__ q,
    const bf16s* __restrict__ k, const bf16s* __restrict__ v, bf16s* __restrict__ o) {
  int n = blockIdx.x, tid = threadIdx.x;
  int h = tid >> 6, lane = tid & 63;
  __shared__ float s[4][9];
  size_t base = (size_t)n * 3 * Dd;
  #pragma unroll
  for (int i = 0; i < 3; i++)
    #pragma unroll
    for (int j = 0; j < 3; j++) {
      float d = 0.f;
      #pragma unroll
      for (int uu = 0; uu < 4; uu++) {
        int u = lane + uu*64;
        d = fmaf(bf2f(q[base + i*Dd + h*256 + u]), bf2f(k[base + j*Dd + h*256 + u]), d);
      }
      #pragma unroll
      for (int off = 32; off; off >>= 1) d += __shfl_xor(d, off, 64);
      if (lane == 0) s[h][i*3 + j] = d * 0.0625f;
    }
  __syncthreads();
  #pragma unroll
  for (int i = 0; i < 3; i++) {
    float s0 = s[h][i*3+0], s1 = s[h][i*3+1], s2 = s[h][i*3+2];
    float m = fmaxf(s0, fmaxf(s1, s2));
    float e0 = __expf(s0 - m), e1 = __expf(s1 - m), e2 = __expf(s2 - m);
    float inv = 1.f / (e0 + e1 + e2);
    e0 *= inv; e1 *= inv; e2 *= inv;
    #pragma unroll
    for (int dd = 0; dd < 4; dd++) {
      int u = lane + dd*64;
      float ov = e0 * bf2f(v[base + 0*Dd + h*256 + u])
               + e1 * bf2f(v[base + 1*Dd + h*256 + u])
               + e2 * bf2f(v[base + 2*Dd + h*256 + u]);
      o[base + i*Dd + h*256 + u] = f2bf(ov);
    }
  }
}

// ---------------- gated fusion (seq f32 -> fused bf16) -----------------------
__global__ __launch_bounds__(256) void fusion_k(const float* __restrict__ seq,
    const float* __restrict__ tp, const float* __restrict__ fg_w,
    const float* __restrict__ fg_b, bf16s* __restrict__ fused) {
  __shared__ float red[256];
  int n = blockIdx.x, tid = threadIdx.x;
  const float* med = seq + (size_t)n * 3 * Dd;
  const float* ex0 = med + Dd;
  const float* ex1 = med + 2*Dd;
  float4 m4 = ((const float4*)med)[tid];
  float4 w4 = ((const float4*)fg_w)[tid];
  float part = m4.x*w4.x + m4.y*w4.y + m4.z*w4.z + m4.w*w4.w;
  float dot = blockReduceSum256(part, red);
  float g = 1.f / (1.f + __expf(-(dot + fg_b[0])));
  float p0 = tp[n*2], p1 = tp[n*2+1];
  float4 e0 = ((const float4*)ex0)[tid];
  float4 e1 = ((const float4*)ex1)[tid];
  s4 r;
  r[0] = f2bf(g*m4.x + (1.f-g)*(p0*e0.x + p1*e1.x));
  r[1] = f2bf(g*m4.y + (1.f-g)*(p0*e0.y + p1*e1.y));
  r[2] = f2bf(g*m4.z + (1.f-g)*(p0*e0.z + p1*e1.z));
  r[3] = f2bf(g*m4.w + (1.f-g)*(p0*e0.w + p1*e1.w));
  ((s4*)fused)[(size_t)n*256 + tid] = r;
}

// ---------------- host launch ----------------
extern "C" void kernel_launch(void* const* d_in, const int* in_sizes, int n_in,
                              void* d_out, int out_size, void* d_ws, size_t ws_size,
                              hipStream_t stream) {
  const float* x_in   = (const float*)d_in[0];
  const float* fcos   = (const float*)d_in[1];
  const float* fsin   = (const float*)d_in[2];
  const float* ln1_w  = (const float*)d_in[3];
  const float* ln2_w  = (const float*)d_in[4];
  const float* w_qkv  = (const float*)d_in[5];
  const float* w_o    = (const float*)d_in[6];
  const float* gate_w = (const float*)d_in[7];
  const float* e_w13  = (const float*)d_in[8];
  const float* e_w2   = (const float*)d_in[9];
  const float* medi   = (const float*)d_in[10];
  const float* mwq    = (const float*)d_in[11];
  const float* mwk    = (const float*)d_in[12];
  const float* mwv    = (const float*)d_in[13];
  const float* mbq    = (const float*)d_in[14];
  const float* mbk    = (const float*)d_in[15];
  const float* mbv    = (const float*)d_in[16];
  const float* mwo    = (const float*)d_in[17];
  const float* mbo    = (const float*)d_in[18];
  const float* cn1_w  = (const float*)d_in[19];
  const float* cn2_w  = (const float*)d_in[20];
  const float* cf1_w  = (const float*)d_in[21];
  const float* cf2_w  = (const float*)d_in[22];
  const float* fg_w   = (const float*)d_in[23];
  const float* fg_b   = (const float*)d_in[24];
  const float* moe_ow = (const float*)d_in[25];

  char* ws = (char*)d_ws;
  bf16s* w13t  = (bf16s*)(ws + B_W13T);
  bf16s* w2t   = (bf16s*)(ws + B_W2T);
  bf16s* wqkvt = (bf16s*)(ws + B_WQKVT);
  bf16s* wot   = (bf16s*)(ws + B_WOT);
  bf16s* mwqt  = (bf16s*)(ws + B_MWQT);
  bf16s* mwkt  = (bf16s*)(ws + B_MWKT);
  bf16s* mwvt  = (bf16s*)(ws + B_MWVT);
  bf16s* mwot  = (bf16s*)(ws + B_MWOT);
  bf16s* cf1t  = (bf16s*)(ws + B_CF1T);
  bf16s* cf2t  = (bf16s*)(ws + B_CF2T);
  bf16s* moet  = (bf16s*)(ws + B_MOET);
  float* x1    = (float*)(ws + B_X1);
  float* xn    = (float*)(ws + B_XN);
  bf16s* xnb   = (bf16s*)(ws + B_XNB);
  float* seq   = (float*)(ws + B_SEQ);
  float* tp    = (float*)(ws + B_TP);
  float* prio  = (float*)(ws + B_PRIO);
  float* scal  = (float*)(ws + B_SCAL);
  int*   eids  = (int*)(ws + B_EIDS);
  int*   rowl  = (int*)(ws + B_ROWL);
  char*  big   = ws + B_BIG;
  bf16s* hnb   = (bf16s*)(big + BG_HNB);
  float* qkvb  = (float*)(big + BG_QKVB);
  bf16s* qk16  = (bf16s*)(big + BG_QK16);
  bf16s* yb    = (bf16s*)(big + BG_YB);
  bf16s* xg    = (bf16s*)(big + BG_XG);
  bf16s* actb  = (bf16s*)(big + BG_ACTB);
  bf16s* nrmb  = (bf16s*)(big + BG_NRM);
  bf16s* cqb   = (bf16s*)(big + BG_CQ);
  bf16s* ckb   = (bf16s*)(big + BG_CK);
  bf16s* cvb   = (bf16s*)(big + BG_CV);
  bf16s* atnob = (bf16s*)(big + BG_ATNO);
  bf16s* ffhb  = (bf16s*)(big + BG_FFH);
  bf16s* fuseb = (bf16s*)(big + BG_FUSE);

  float* out_x   = (float*)d_out;
  float* out_aux = out_x + (size_t)NTOK * Dd;

  dim3 blk(256);

  init_k<<<dim3(32), blk, 0, stream>>>(scal, rowl);

  // weight transposes (f32 [K][N] -> bf16 [N][K])
  transpose_cast_k<<<dim3(QKVD/32, Dd/32), blk, 0, stream>>>(w_qkv, wqkvt, Dd, QKVD, 0, 0);
  transpose_cast_k<<<dim3(Dd/32, Dd/32), blk, 0, stream>>>(w_o,  wot,  Dd, Dd, 0, 0);
  transpose_cast_k<<<dim3(Dd/32, Dd/32), blk, 0, stream>>>(mwq,  mwqt, Dd, Dd, 0, 0);
  transpose_cast_k<<<dim3(Dd/32, Dd/32), blk, 0, stream>>>(mwk,  mwkt, Dd, Dd, 0, 0);
  transpose_cast_k<<<dim3(Dd/32, Dd/32), blk, 0, stream>>>(mwv,  mwvt, Dd, Dd, 0, 0);
  transpose_cast_k<<<dim3(Dd/32, Dd/32), blk, 0, stream>>>(mwo,  mwot, Dd, Dd, 0, 0);
  transpose_cast_k<<<dim3(Dd/32, Dd/32), blk, 0, stream>>>(cf1_w, cf1t, Dd, Dd, 0, 0);
  transpose_cast_k<<<dim3(Dd/32, Dd/32), blk, 0, stream>>>(cf2_w, cf2t, Dd, Dd, 0, 0);
  transpose_cast_k<<<dim3(Dd/32, Dd/32), blk, 0, stream>>>(moe_ow, moet, Dd, Dd, 0, 0);
  transpose_cast_k<<<dim3(2*HID/32, Dd/32, Ee), blk, 0, stream>>>(
      e_w13, w13t, Dd, 2*HID, (size_t)Dd*2*HID, (size_t)2*HID*Dd);
  transpose_cast_k<<<dim3(Dd/32, HID/32, Ee), blk, 0, stream>>>(
      e_w2, w2t, HID, Dd, (size_t)HID*Dd, (size_t)Dd*HID);

  // attention block
  rmsnorm_k<<<dim3(NTOK), blk, 0, stream>>>(x_in, ln1_w, (float*)nullptr, hnb);
  gemm_bt<false,false><<<dim3(QKVD/128, NTOK/128), blk, 0, stream>>>(
      hnb, wqkvt, nullptr, nullptr, qkvb, NTOK, QKVD, Dd);
  rope_cast_k<<<dim3((NTOK*(QKVD/2))/256), blk, 0, stream>>>(qkvb, fcos, fsin, qk16);
  attn_mfma_k<<<dim3(Tt/64, Hh, Bb), blk, 0, stream>>>(qk16, yb);
  gemm_bt<false,false><<<dim3(Dd/128, NTOK/128), blk, 0, stream>>>(
      yb, wot, nullptr, x_in, x1, NTOK, Dd, Dd);

  // routing
  rmsnorm_k<<<dim3(NTOK), blk, 0, stream>>>(x1, ln2_w, xn, xnb);
  route_k<<<dim3(NTOK), dim3(64), 0, stream>>>(xn, gate_w, tp, prio, eids, scal);
  rank_k<<<dim3(NK/256), blk, 0, stream>>>(eids, prio, rowl);
  aux_k<<<dim3(1), dim3(64), 0, stream>>>(scal, out_aux);

  // expert FFN
  gather_k<<<dim3(Ee*CAP*(Dd/4)/256), blk, 0, stream>>>(xnb, rowl, xg);
  seqfill_k<<<dim3(NTOK*3*(Dd/4)/256), blk, 0, stream>>>(medi, seq);
  gemm_w13<<<dim3(HID/64, CAP/128, Ee), blk, 0, stream>>>(xg, w13t, rowl, actb);
  gemm_w2<<<dim3(Dd/128, CAP/128, Ee), blk, 0, stream>>>(actb, w2t, xn, rowl, seq);

  // collab transformer (2 rounds)
  for (int r = 0; r < 2; r++) {
    rmsnorm_k<<<dim3(NTOK*3), blk, 0, stream>>>(seq, cn1_w, (float*)nullptr, nrmb);
    gemm_bt<true,false><<<dim3(Dd/128, NTOK*3/128), blk, 0, stream>>>(
        nrmb, mwqt, mbq, nullptr, cqb, NTOK*3, Dd, Dd);
    gemm_bt<true,false><<<dim3(Dd/128, NTOK*3/128), blk, 0, stream>>>(
        nrmb, mwkt, mbk, nullptr, ckb, NTOK*3, Dd, Dd);
    gemm_bt<true,false><<<dim3(Dd/128, NTOK*3/128), blk, 0, stream>>>(
        nrmb, mwvt, mbv, nullptr, cvb, NTOK*3, Dd, Dd);
    collab_attn_k<<<dim3(NTOK), blk, 0, stream>>>(cqb, ckb, cvb, atnob);
    gemm_bt<false,false><<<dim3(Dd/128, NTOK*3/128), blk, 0, stream>>>(
        atnob, mwot, mbo, seq, seq, NTOK*3, Dd, Dd);
    rmsnorm_k<<<dim3(NTOK*3), blk, 0, stream>>>(seq, cn2_w, (float*)nullptr, nrmb);
    gemm_bt<true,true><<<dim3(Dd/128, NTOK*3/128), blk, 0, stream>>>(
        nrmb, cf1t, nullptr, nullptr, ffhb, NTOK*3, Dd, Dd);
    gemm_bt<false,false><<<dim3(Dd/128, NTOK*3/128), blk, 0, stream>>>(
        ffhb, cf2t, nullptr, seq, seq, NTOK*3, Dd, Dd);
  }

  // fusion + final projection
  fusion_k<<<dim3(NTOK), blk, 0, stream>>>(seq, tp, fg_w, fg_b, fuseb);
  gemm_bt<false,false><<<dim3(Dd/128, NTOK/128), blk, 0, stream>>>(
      fuseb, moet, nullptr, x1, out_x, NTOK, Dd, Dd);
}